// Round 10
// baseline (206.427 us; speedup 1.0000x reference)
//
#include <hip/hip_runtime.h>
#include <hip/hip_bf16.h>
#include <stdint.h>

typedef __bf16 bf16;
typedef __attribute__((ext_vector_type(8))) __bf16 bf16x8;
typedef __attribute__((ext_vector_type(4))) __bf16 bf16x4;
typedef __attribute__((ext_vector_type(4))) float f32x4;

constexpr int Bn = 4, Tn = 2048, Cn = 1024, Hn = 16, HD = 64;
constexpr int Mn = Bn * Tn; // 8192

__device__ __forceinline__ void gl_lds16(const void* g, void* l) {
  __builtin_amdgcn_global_load_lds(
      (const __attribute__((address_space(1))) void*)g,
      (__attribute__((address_space(3))) void*)l, 16u, 0, 0u);
}

// ---------------- x (fp32) -> bf16 ----------------
__global__ __launch_bounds__(256) void k_cvt_x(const float* __restrict__ x,
                                               bf16* __restrict__ xb) {
  int i = (blockIdx.x * 256 + threadIdx.x) * 8;
  float4 a = *(const float4*)(x + i);
  float4 b = *(const float4*)(x + i + 4);
  bf16x8 v;
  v[0] = (bf16)a.x; v[1] = (bf16)a.y; v[2] = (bf16)a.z; v[3] = (bf16)a.w;
  v[4] = (bf16)b.x; v[5] = (bf16)b.y; v[6] = (bf16)b.z; v[7] = (bf16)b.w;
  *(bf16x8*)(xb + i) = v;
}

// ---------------- W [K][N] fp32 -> WT [N][K] bf16 ----------------
__global__ __launch_bounds__(256) void k_tw(const float* __restrict__ W0,
                                            const float* __restrict__ W1,
                                            const float* __restrict__ W2,
                                            const float* __restrict__ W3,
                                            bf16* __restrict__ WT) {
  __shared__ float tile[32][33];
  const float* W = (blockIdx.z == 0) ? W0 : (blockIdx.z == 1) ? W1
                  : (blockIdx.z == 2) ? W2 : W3;
  bf16* out = WT + (size_t)blockIdx.z * Cn * Cn;
  int tx = threadIdx.x & 31, ty = threadIdx.x >> 5;  // 32 x 8
  int gx = blockIdx.x * 32 + tx;   // n
  int gy = blockIdx.y * 32;        // k
#pragma unroll
  for (int j = 0; j < 32; j += 8)
    tile[ty + j][tx] = W[(size_t)(gy + ty + j) * Cn + gx];
  __syncthreads();
  int ox = blockIdx.y * 32 + tx;   // k
  int oy = blockIdx.x * 32;        // n
#pragma unroll
  for (int j = 0; j < 32; j += 8)
    out[(size_t)(oy + ty + j) * Cn + ox] = (bf16)tile[tx][ty + j];
}

// ---------------- fused QKV GEMM: N = 3072 (Wq|Wk|Wv stacked in WT) -------
// 1D grid, XCD-strip swizzle: XCD k owns cols [3k,3k+3) for all 64 row-blocks
// -> 768KB B-slice stays L2-resident; A panels stream with 3x in-L2 reuse.
__global__ __launch_bounds__(256) void k_gemm_qkv(const bf16* __restrict__ A,
                                                  const bf16* __restrict__ BT,
                                                  const float* __restrict__ bq,
                                                  const float* __restrict__ bk,
                                                  const float* __restrict__ bv,
                                                  bf16* __restrict__ out,
                                                  float qscale) {
  constexpr int KD = 1024;
  __shared__ __align__(16) bf16 As[128 * 64];
  __shared__ __align__(16) bf16 Bs[128 * 64];
  const int t = threadIdx.x;
  const int w = t >> 6, l = t & 63;
  const int b = blockIdx.x;
  const int k8 = b & 7, j = b >> 3;
  const int m0 = (j / 3) * 128, n0 = (3 * k8 + j % 3) * 128;
  const int wr = (w >> 1) * 64, wc = (w & 1) * 64;
  f32x4 acc[4][4] = {};

  for (int kt = 0; kt < KD; kt += 64) {
    __syncthreads();
#pragma unroll
    for (int i = 0; i < 4; ++i) {
      int c = i * 256 + t;
      int row = c >> 3;
      int seg = (c & 7) ^ (row & 7);
      gl_lds16(A + (size_t)(m0 + row) * KD + kt + seg * 8,
               (char*)As + i * 4096 + w * 1024);
      gl_lds16(BT + (size_t)(n0 + row) * KD + kt + seg * 8,
               (char*)Bs + i * 4096 + w * 1024);
    }
    __syncthreads();
#pragma unroll
    for (int kc = 0; kc < 2; ++kc) {
      bf16x8 af[4], bg[4];
#pragma unroll
      for (int mi = 0; mi < 4; ++mi) {
        int row = wr + mi * 16 + (l & 15);
        int off = (row * 128 + kc * 64 + (l >> 4) * 16) ^ ((row & 7) << 4);
        af[mi] = *(const bf16x8*)((const char*)As + off);
      }
#pragma unroll
      for (int ni = 0; ni < 4; ++ni) {
        int row = wc + ni * 16 + (l & 15);
        int off = (row * 128 + kc * 64 + (l >> 4) * 16) ^ ((row & 7) << 4);
        bg[ni] = *(const bf16x8*)((const char*)Bs + off);
      }
#pragma unroll
      for (int mi = 0; mi < 4; ++mi)
#pragma unroll
        for (int ni = 0; ni < 4; ++ni)
          acc[mi][ni] = __builtin_amdgcn_mfma_f32_16x16x32_bf16(
              af[mi], bg[ni], acc[mi][ni], 0, 0, 0);
    }
  }
  const int q16l = l & 15;
#pragma unroll
  for (int ni = 0; ni < 4; ++ni) {
    int colBase = n0 + wc + ni * 16;           // multiple of 16
    int which = colBase >> 10;                 // 0=Q 1=K 2=V (uniform per ni)
    const float* bp = (which == 0) ? bq : (which == 1) ? bk : bv;
    float scl = (which == 0) ? qscale : 1.0f;
    float bval = bp[(colBase & 1023) + q16l];
    int hh = (colBase >> 6) & 15;
    int dd = (colBase & 63) + q16l;
    size_t obase = (size_t)which * 8388608 + (size_t)hh * (Tn * HD) + dd;
#pragma unroll
    for (int mi = 0; mi < 4; ++mi) {
#pragma unroll
      for (int r = 0; r < 4; ++r) {
        int row = m0 + wr + mi * 16 + (l >> 4) * 4 + r;
        int bb = row >> 11, tt = row & 2047;
        float v = (acc[mi][ni][r] + bval) * scl;
        out[obase + ((size_t)bb * Hn * Tn + tt) * HD] = (bf16)v;
      }
    }
  }
}

// ---------------- output projection GEMM: out fp32 flat [M][C] ----------
// 1D grid, XCD-strip swizzle: XCD k owns col k for all row-blocks.
__global__ __launch_bounds__(256) void k_gemm_o(const bf16* __restrict__ A,
                                                const bf16* __restrict__ BT,
                                                const float* __restrict__ bias,
                                                float* __restrict__ out) {
  constexpr int KD = 1024;
  __shared__ __align__(16) bf16 As[128 * 64];
  __shared__ __align__(16) bf16 Bs[128 * 64];
  const int t = threadIdx.x;
  const int w = t >> 6, l = t & 63;
  const int b = blockIdx.x;
  const int m0 = (b >> 3) * 128, n0 = (b & 7) * 128;
  const int wr = (w >> 1) * 64, wc = (w & 1) * 64;
  f32x4 acc[4][4] = {};

  for (int kt = 0; kt < KD; kt += 64) {
    __syncthreads();
#pragma unroll
    for (int i = 0; i < 4; ++i) {
      int c = i * 256 + t;
      int row = c >> 3;
      int seg = (c & 7) ^ (row & 7);
      gl_lds16(A + (size_t)(m0 + row) * KD + kt + seg * 8,
               (char*)As + i * 4096 + w * 1024);
      gl_lds16(BT + (size_t)(n0 + row) * KD + kt + seg * 8,
               (char*)Bs + i * 4096 + w * 1024);
    }
    __syncthreads();
#pragma unroll
    for (int kc = 0; kc < 2; ++kc) {
      bf16x8 af[4], bg[4];
#pragma unroll
      for (int mi = 0; mi < 4; ++mi) {
        int row = wr + mi * 16 + (l & 15);
        int off = (row * 128 + kc * 64 + (l >> 4) * 16) ^ ((row & 7) << 4);
        af[mi] = *(const bf16x8*)((const char*)As + off);
      }
#pragma unroll
      for (int ni = 0; ni < 4; ++ni) {
        int row = wc + ni * 16 + (l & 15);
        int off = (row * 128 + kc * 64 + (l >> 4) * 16) ^ ((row & 7) << 4);
        bg[ni] = *(const bf16x8*)((const char*)Bs + off);
      }
#pragma unroll
      for (int mi = 0; mi < 4; ++mi)
#pragma unroll
        for (int ni = 0; ni < 4; ++ni)
          acc[mi][ni] = __builtin_amdgcn_mfma_f32_16x16x32_bf16(
              af[mi], bg[ni], acc[mi][ni], 0, 0, 0);
    }
  }
#pragma unroll
  for (int ni = 0; ni < 4; ++ni) {
    int col = n0 + wc + ni * 16 + (l & 15);
    float bv = bias[col];
#pragma unroll
    for (int mi = 0; mi < 4; ++mi) {
#pragma unroll
      for (int r = 0; r < 4; ++r) {
        int row = m0 + wr + mi * 16 + (l >> 4) * 4 + r;
        out[(size_t)row * Cn + col] = acc[mi][ni][r] + bv;
      }
    }
  }
}

// ---------------- flash attention (causal), 8-wave QBLK=128 ----------------
// Q pre-scaled by 0.125*log2e -> softmax in base-2.
// 512 threads, QBLK=128 (wave w owns q rows qtile*128 + w*16 + [0,16)),
// KVBLK=64, LDS 32KB (4 blocks x 8 waves = 32 waves/CU possible).
// Per-wave causal handling: tiles fully below diagonal -> full compute;
// the single diagonal tile -> masked with diag=(w&3)*16+q16; tiles beyond
// -> compute skipped (barriers/staging preserved).
// LDS banks: Ks0@0  Ks1@8192  Vt0@16384  Vt1@24576.
__global__ __launch_bounds__(512, 8) void k_attn(const bf16* __restrict__ Q,
                                                 const bf16* __restrict__ K,
                                                 const bf16* __restrict__ V,
                                                 bf16* __restrict__ Y) {
  __shared__ __align__(16) char smem[32768];
  const int t = threadIdx.x, w = t >> 6, l = t & 63;
  const int g = l >> 4, q16 = l & 15;
  const int wg = blockIdx.x;
  const int bh = wg & 63;                      // low bits -> XCD pinning
  const int qtile = 15 - (wg >> 6);            // heavy tiles first
  const size_t base = (size_t)bh * Tn * HD;
  const bf16* Qh = Q + base;
  const bf16* Vh = V + base;
  const int qg = qtile * 128 + w * 16 + q16;   // this lane's q row

  bf16x8 aq[2];
#pragma unroll
  for (int kc = 0; kc < 2; ++kc)
    aq[kc] = *(const bf16x8*)(Qh + (size_t)qg * HD + kc * 32 + g * 8);

  // LDS read bases (loop-invariant)
  const int xm = (q16 & 7) << 4;
  const int qkB0 = q16 * 128 + ((g * 16) ^ xm);        // kc/vkc = 0
  const int qkB1 = q16 * 128 + ((64 + g * 16) ^ xm);   // kc/vkc = 1
  // V scatter bases: wave w writes d = w*8 + j, kv = l
  const int innerL = (l >> 5) * 64 + ((l & 15) >> 2) * 16 +
                     (((l >> 4) & 1) * 4 + (l & 3)) * 2;
  int stb[8];
#pragma unroll
  for (int j = 0; j < 8; ++j)
    stb[j] = w * 1024 + j * 128 + (innerL ^ (j << 4));

  // K staging: thread handles LDS slot t (dest base w*1024, lane*16 implied)
  const int krow = w * 8 + (l >> 3);
  const int kseg = (l & 7) ^ (krow & 7);
  const bf16* kP = K + base + (size_t)krow * HD + kseg * 8;
  const bf16* vP = Vh + (size_t)l * HD + w * 8;

  f32x4 yacc[4] = {};
  float m_ = -1e30f, l_ = 0.f;
  const int nt = 2 * qtile + 2;
  const int it_mask = 2 * qtile + (w >= 4 ? 1 : 0);
  const int diag = (w & 3) * 16 + q16;

#define STAGE_K(KBUF)                           \
  {                                             \
    gl_lds16(kP, smem + (KBUF) + w * 1024);     \
    kP += 4096;                                 \
  }
#define WRITE_V(VBUF, a0)                               \
  {                                                     \
    _Pragma("unroll") for (int j = 0; j < 8; ++j)       \
      *(bf16*)(smem + (VBUF) + stb[j]) = a0[j];         \
  }
#define COMPUTE(KBUF, VBUF, DOMASK)                                          \
  {                                                                          \
    f32x4 s[4] = {};                                                         \
    __builtin_amdgcn_s_setprio(1);                                           \
    _Pragma("unroll") for (int nj = 0; nj < 4; ++nj) {                       \
      bf16x8 ak0 = *(const bf16x8*)(smem + (KBUF) + qkB0 + nj * 2048);       \
      s[nj] = __builtin_amdgcn_mfma_f32_16x16x32_bf16(ak0, aq[0], s[nj], 0, 0, 0); \
      bf16x8 ak1 = *(const bf16x8*)(smem + (KBUF) + qkB1 + nj * 2048);       \
      s[nj] = __builtin_amdgcn_mfma_f32_16x16x32_bf16(ak1, aq[1], s[nj], 0, 0, 0); \
    }                                                                        \
    __builtin_amdgcn_s_setprio(0);                                           \
    if (DOMASK) {                                                            \
      _Pragma("unroll") for (int nj = 0; nj < 4; ++nj)                       \
        _Pragma("unroll") for (int r = 0; r < 4; ++r)                        \
          if (nj * 16 + g * 4 + r > diag) s[nj][r] = -1e30f;                 \
    }                                                                        \
    float mx = fmaxf(fmaxf(fmaxf(s[0][0], s[0][1]), fmaxf(s[0][2], s[0][3])),\
                     fmaxf(fmaxf(s[1][0], s[1][1]), fmaxf(s[1][2], s[1][3])));\
    mx = fmaxf(mx, fmaxf(fmaxf(fmaxf(s[2][0], s[2][1]), fmaxf(s[2][2], s[2][3])),\
                         fmaxf(fmaxf(s[3][0], s[3][1]), fmaxf(s[3][2], s[3][3]))));\
    mx = fmaxf(mx, __shfl_xor(mx, 16));                                      \
    mx = fmaxf(mx, __shfl_xor(mx, 32));                                      \
    float mn = fmaxf(m_, mx);                                                \
    float fac = __builtin_amdgcn_exp2f(m_ - mn);                             \
    m_ = mn;                                                                 \
    float rs = 0.f;                                                          \
    _Pragma("unroll") for (int nj = 0; nj < 4; ++nj)                         \
      _Pragma("unroll") for (int r = 0; r < 4; ++r) {                        \
        float pv = __builtin_amdgcn_exp2f(s[nj][r] - mn);                    \
        s[nj][r] = pv;                                                       \
        rs += pv;                                                            \
      }                                                                      \
    rs += __shfl_xor(rs, 16);                                                \
    rs += __shfl_xor(rs, 32);                                                \
    l_ = l_ * fac + rs;                                                      \
    _Pragma("unroll") for (int ni = 0; ni < 4; ++ni)                         \
      _Pragma("unroll") for (int r = 0; r < 4; ++r) yacc[ni][r] *= fac;      \
    __builtin_amdgcn_s_setprio(1);                                           \
    _Pragma("unroll") for (int vkc = 0; vkc < 2; ++vkc) {                    \
      bf16x8 pb;                                                             \
      _Pragma("unroll") for (int j = 0; j < 4; ++j) {                        \
        pb[j] = (bf16)s[2 * vkc][j];                                         \
        pb[4 + j] = (bf16)s[2 * vkc + 1][j];                                 \
      }                                                                      \
      int vb = (vkc == 0) ? qkB0 : qkB1;                                     \
      _Pragma("unroll") for (int ni = 0; ni < 4; ++ni) {                     \
        bf16x8 va = *(const bf16x8*)(smem + (VBUF) + vb + ni * 2048);        \
        yacc[ni] = __builtin_amdgcn_mfma_f32_16x16x32_bf16(va, pb, yacc[ni], 0, 0, 0); \
      }                                                                      \
    }                                                                        \
    __builtin_amdgcn_s_setprio(0);                                           \
  }

  // prologue: tile 0 -> bank 0
  STAGE_K(0);
  {
    bf16x8 a0 = *(const bf16x8*)vP;
    vP += 4096;
    WRITE_V(16384, a0);
  }

  int it = 0;
  for (;;) {
    // even phase: compute bank0, prefetch -> bank1
    __syncthreads();
    bool more = (it + 1) < nt;
    bf16x8 a0;
    if (more) {
      STAGE_K(8192);
      a0 = *(const bf16x8*)vP;
      vP += 4096;
    }
    if (it <= it_mask) COMPUTE(0, 16384, it == it_mask);
    if (more) WRITE_V(24576, a0);
    if (++it >= nt) break;

    // odd phase: compute bank1, prefetch -> bank0
    __syncthreads();
    more = (it + 1) < nt;
    if (more) {
      STAGE_K(0);
      a0 = *(const bf16x8*)vP;
      vP += 4096;
    }
    if (it <= it_mask) COMPUTE(8192, 24576, it == it_mask);
    if (more) WRITE_V(16384, a0);
    if (++it >= nt) break;
  }
#undef STAGE_K
#undef WRITE_V
#undef COMPUTE

  // epilogue: lane owns q = qg; d = ni*16 + g*4 + r (contiguous in r)
  const int hh = bh & 15, bb = bh >> 4;
  float inv = 1.f / l_;
#pragma unroll
  for (int ni = 0; ni < 4; ++ni) {
    bf16x4 o;
#pragma unroll
    for (int r = 0; r < 4; ++r) o[r] = (bf16)(yacc[ni][r] * inv);
    int d0 = ni * 16 + g * 4;
    *(bf16x4*)&Y[(size_t)(bb * Tn + qg) * Cn + hh * HD + d0] = o;
  }
}

extern "C" void kernel_launch(void* const* d_in, const int* in_sizes, int n_in,
                              void* d_out, int out_size, void* d_ws,
                              size_t ws_size, hipStream_t stream) {
  const float* x  = (const float*)d_in[0];
  const float* Wq = (const float*)d_in[1];
  const float* bq = (const float*)d_in[2];
  const float* Wk = (const float*)d_in[3];
  const float* bk = (const float*)d_in[4];
  const float* Wv = (const float*)d_in[5];
  const float* bv = (const float*)d_in[6];
  const float* Wo = (const float*)d_in[7];
  const float* bo = (const float*)d_in[8];
  char* ws = (char*)d_ws;
  bf16* xb = (bf16*)ws;                          // 16MB, reused as y
  bf16* WT = (bf16*)(ws + (size_t)(16 << 20));   // 8MB (4 x 1M elems)
  bf16* Qh = (bf16*)(ws + (size_t)(24 << 20));   // 16MB (K,V follow)
  bf16* Kh = (bf16*)(ws + (size_t)(40 << 20));
  bf16* Vh = (bf16*)(ws + (size_t)(56 << 20));
  float* out = (float*)d_out;                    // reference output is fp32

  const float QSCALE = 0.125f * 1.44269504088896f;  // 1/sqrt(64) * log2(e)

  k_cvt_x<<<4096, 256, 0, stream>>>(x, xb);
  k_tw<<<dim3(32, 32, 4), 256, 0, stream>>>(Wq, Wk, Wv, Wo, WT);
  k_gemm_qkv<<<1536, 256, 0, stream>>>(xb, WT, bq, bk, bv, Qh, QSCALE);
  k_attn<<<1024, 512, 0, stream>>>(Qh, Kh, Vh, xb);
  k_gemm_o<<<512, 256, 0, stream>>>(xb, WT + (3u << 20), bo, out);
}

// Round 11
// 161.418 us; speedup vs baseline: 1.2788x; 1.2788x over previous
//
#include <hip/hip_runtime.h>
#include <hip/hip_bf16.h>
#include <stdint.h>

typedef __bf16 bf16;
typedef __attribute__((ext_vector_type(8))) __bf16 bf16x8;
typedef __attribute__((ext_vector_type(4))) __bf16 bf16x4;
typedef __attribute__((ext_vector_type(4))) float f32x4;

constexpr int Bn = 4, Tn = 2048, Cn = 1024, Hn = 16, HD = 64;
constexpr int Mn = Bn * Tn; // 8192

__device__ __forceinline__ void gl_lds16(const void* g, void* l) {
  __builtin_amdgcn_global_load_lds(
      (const __attribute__((address_space(1))) void*)g,
      (__attribute__((address_space(3))) void*)l, 16u, 0, 0u);
}

// ---------------- x (fp32) -> bf16 ----------------
__global__ __launch_bounds__(256) void k_cvt_x(const float* __restrict__ x,
                                               bf16* __restrict__ xb) {
  int i = (blockIdx.x * 256 + threadIdx.x) * 8;
  float4 a = *(const float4*)(x + i);
  float4 b = *(const float4*)(x + i + 4);
  bf16x8 v;
  v[0] = (bf16)a.x; v[1] = (bf16)a.y; v[2] = (bf16)a.z; v[3] = (bf16)a.w;
  v[4] = (bf16)b.x; v[5] = (bf16)b.y; v[6] = (bf16)b.z; v[7] = (bf16)b.w;
  *(bf16x8*)(xb + i) = v;
}

// ---------------- W [K][N] fp32 -> WT [N][K] bf16 ----------------
__global__ __launch_bounds__(256) void k_tw(const float* __restrict__ W0,
                                            const float* __restrict__ W1,
                                            const float* __restrict__ W2,
                                            const float* __restrict__ W3,
                                            bf16* __restrict__ WT) {
  __shared__ float tile[32][33];
  const float* W = (blockIdx.z == 0) ? W0 : (blockIdx.z == 1) ? W1
                  : (blockIdx.z == 2) ? W2 : W3;
  bf16* out = WT + (size_t)blockIdx.z * Cn * Cn;
  int tx = threadIdx.x & 31, ty = threadIdx.x >> 5;  // 32 x 8
  int gx = blockIdx.x * 32 + tx;   // n
  int gy = blockIdx.y * 32;        // k
#pragma unroll
  for (int j = 0; j < 32; j += 8)
    tile[ty + j][tx] = W[(size_t)(gy + ty + j) * Cn + gx];
  __syncthreads();
  int ox = blockIdx.y * 32 + tx;   // k
  int oy = blockIdx.x * 32;        // n
#pragma unroll
  for (int j = 0; j < 32; j += 8)
    out[(size_t)(oy + ty + j) * Cn + ox] = (bf16)tile[tx][ty + j];
}

// ---------------- fused QKV GEMM: N = 3072 (Wq|Wk|Wv stacked in WT) -------
// 1D grid, XCD-strip swizzle: XCD k owns cols [3k,3k+3) for all 64 row-blocks
// -> 768KB B-slice stays L2-resident; A panels stream with 3x in-L2 reuse.
__global__ __launch_bounds__(256) void k_gemm_qkv(const bf16* __restrict__ A,
                                                  const bf16* __restrict__ BT,
                                                  const float* __restrict__ bq,
                                                  const float* __restrict__ bk,
                                                  const float* __restrict__ bv,
                                                  bf16* __restrict__ out,
                                                  float qscale) {
  constexpr int KD = 1024;
  __shared__ __align__(16) bf16 As[128 * 64];
  __shared__ __align__(16) bf16 Bs[128 * 64];
  const int t = threadIdx.x;
  const int w = t >> 6, l = t & 63;
  const int b = blockIdx.x;
  const int k8 = b & 7, j = b >> 3;
  const int m0 = (j / 3) * 128, n0 = (3 * k8 + j % 3) * 128;
  const int wr = (w >> 1) * 64, wc = (w & 1) * 64;
  f32x4 acc[4][4] = {};

  for (int kt = 0; kt < KD; kt += 64) {
    __syncthreads();
#pragma unroll
    for (int i = 0; i < 4; ++i) {
      int c = i * 256 + t;
      int row = c >> 3;
      int seg = (c & 7) ^ (row & 7);
      gl_lds16(A + (size_t)(m0 + row) * KD + kt + seg * 8,
               (char*)As + i * 4096 + w * 1024);
      gl_lds16(BT + (size_t)(n0 + row) * KD + kt + seg * 8,
               (char*)Bs + i * 4096 + w * 1024);
    }
    __syncthreads();
#pragma unroll
    for (int kc = 0; kc < 2; ++kc) {
      bf16x8 af[4], bg[4];
#pragma unroll
      for (int mi = 0; mi < 4; ++mi) {
        int row = wr + mi * 16 + (l & 15);
        int off = (row * 128 + kc * 64 + (l >> 4) * 16) ^ ((row & 7) << 4);
        af[mi] = *(const bf16x8*)((const char*)As + off);
      }
#pragma unroll
      for (int ni = 0; ni < 4; ++ni) {
        int row = wc + ni * 16 + (l & 15);
        int off = (row * 128 + kc * 64 + (l >> 4) * 16) ^ ((row & 7) << 4);
        bg[ni] = *(const bf16x8*)((const char*)Bs + off);
      }
#pragma unroll
      for (int mi = 0; mi < 4; ++mi)
#pragma unroll
        for (int ni = 0; ni < 4; ++ni)
          acc[mi][ni] = __builtin_amdgcn_mfma_f32_16x16x32_bf16(
              af[mi], bg[ni], acc[mi][ni], 0, 0, 0);
    }
  }
  const int q16l = l & 15;
#pragma unroll
  for (int ni = 0; ni < 4; ++ni) {
    int colBase = n0 + wc + ni * 16;           // multiple of 16
    int which = colBase >> 10;                 // 0=Q 1=K 2=V (uniform per ni)
    const float* bp = (which == 0) ? bq : (which == 1) ? bk : bv;
    float scl = (which == 0) ? qscale : 1.0f;
    float bval = bp[(colBase & 1023) + q16l];
    int hh = (colBase >> 6) & 15;
    int dd = (colBase & 63) + q16l;
    size_t obase = (size_t)which * 8388608 + (size_t)hh * (Tn * HD) + dd;
#pragma unroll
    for (int mi = 0; mi < 4; ++mi) {
#pragma unroll
      for (int r = 0; r < 4; ++r) {
        int row = m0 + wr + mi * 16 + (l >> 4) * 4 + r;
        int bb = row >> 11, tt = row & 2047;
        float v = (acc[mi][ni][r] + bval) * scl;
        out[obase + ((size_t)bb * Hn * Tn + tt) * HD] = (bf16)v;
      }
    }
  }
}

// ---------------- output projection GEMM: out fp32 flat [M][C] ----------
// 1D grid, XCD-strip swizzle: XCD k owns col k for all row-blocks.
__global__ __launch_bounds__(256) void k_gemm_o(const bf16* __restrict__ A,
                                                const bf16* __restrict__ BT,
                                                const float* __restrict__ bias,
                                                float* __restrict__ out) {
  constexpr int KD = 1024;
  __shared__ __align__(16) bf16 As[128 * 64];
  __shared__ __align__(16) bf16 Bs[128 * 64];
  const int t = threadIdx.x;
  const int w = t >> 6, l = t & 63;
  const int b = blockIdx.x;
  const int m0 = (b >> 3) * 128, n0 = (b & 7) * 128;
  const int wr = (w >> 1) * 64, wc = (w & 1) * 64;
  f32x4 acc[4][4] = {};

  for (int kt = 0; kt < KD; kt += 64) {
    __syncthreads();
#pragma unroll
    for (int i = 0; i < 4; ++i) {
      int c = i * 256 + t;
      int row = c >> 3;
      int seg = (c & 7) ^ (row & 7);
      gl_lds16(A + (size_t)(m0 + row) * KD + kt + seg * 8,
               (char*)As + i * 4096 + w * 1024);
      gl_lds16(BT + (size_t)(n0 + row) * KD + kt + seg * 8,
               (char*)Bs + i * 4096 + w * 1024);
    }
    __syncthreads();
#pragma unroll
    for (int kc = 0; kc < 2; ++kc) {
      bf16x8 af[4], bg[4];
#pragma unroll
      for (int mi = 0; mi < 4; ++mi) {
        int row = wr + mi * 16 + (l & 15);
        int off = (row * 128 + kc * 64 + (l >> 4) * 16) ^ ((row & 7) << 4);
        af[mi] = *(const bf16x8*)((const char*)As + off);
      }
#pragma unroll
      for (int ni = 0; ni < 4; ++ni) {
        int row = wc + ni * 16 + (l & 15);
        int off = (row * 128 + kc * 64 + (l >> 4) * 16) ^ ((row & 7) << 4);
        bg[ni] = *(const bf16x8*)((const char*)Bs + off);
      }
#pragma unroll
      for (int mi = 0; mi < 4; ++mi)
#pragma unroll
        for (int ni = 0; ni < 4; ++ni)
          acc[mi][ni] = __builtin_amdgcn_mfma_f32_16x16x32_bf16(
              af[mi], bg[ni], acc[mi][ni], 0, 0, 0);
    }
  }
#pragma unroll
  for (int ni = 0; ni < 4; ++ni) {
    int col = n0 + wc + ni * 16 + (l & 15);
    float bv = bias[col];
#pragma unroll
    for (int mi = 0; mi < 4; ++mi) {
#pragma unroll
      for (int r = 0; r < 4; ++r) {
        int row = m0 + wr + mi * 16 + (l >> 4) * 4 + r;
        out[(size_t)row * Cn + col] = acc[mi][ni][r] + bv;
      }
    }
  }
}

// ---------------- flash attention (causal), 8-wave QBLK=128 ----------------
// Q pre-scaled by 0.125*log2e -> softmax in base-2.
// 512 threads, QBLK=128 (wave w owns q rows qtile*128 + w*16 + [0,16)),
// KVBLK=64, LDS 32KB. __launch_bounds__(512, 4): VGPR cap 128 -- round 10's
// (512,8) capped VGPR at 32 and spilled 64MB/dispatch to scratch (WRITE_SIZE
// 80MB, dur +40%). Need ~70 live VGPRs; let HW give 4-8 waves/SIMD naturally.
// Per-wave causal: diagonal tile masked with diag=(w&3)*16+q16; beyond-
// diagonal tiles skip compute (barriers/staging preserved).
// LDS banks: Ks0@0  Ks1@8192  Vt0@16384  Vt1@24576.
__global__ __launch_bounds__(512, 4) void k_attn(const bf16* __restrict__ Q,
                                                 const bf16* __restrict__ K,
                                                 const bf16* __restrict__ V,
                                                 bf16* __restrict__ Y) {
  __shared__ __align__(16) char smem[32768];
  const int t = threadIdx.x, w = t >> 6, l = t & 63;
  const int g = l >> 4, q16 = l & 15;
  const int wg = blockIdx.x;
  const int bh = wg & 63;                      // low bits -> XCD pinning
  const int qtile = 15 - (wg >> 6);            // heavy tiles first
  const size_t base = (size_t)bh * Tn * HD;
  const bf16* Qh = Q + base;
  const bf16* Vh = V + base;
  const int qg = qtile * 128 + w * 16 + q16;   // this lane's q row

  bf16x8 aq[2];
#pragma unroll
  for (int kc = 0; kc < 2; ++kc)
    aq[kc] = *(const bf16x8*)(Qh + (size_t)qg * HD + kc * 32 + g * 8);

  // LDS read bases (loop-invariant)
  const int xm = (q16 & 7) << 4;
  const int qkB0 = q16 * 128 + ((g * 16) ^ xm);        // kc/vkc = 0
  const int qkB1 = q16 * 128 + ((64 + g * 16) ^ xm);   // kc/vkc = 1
  // V scatter bases: wave w writes d = w*8 + j, kv = l
  const int innerL = (l >> 5) * 64 + ((l & 15) >> 2) * 16 +
                     (((l >> 4) & 1) * 4 + (l & 3)) * 2;
  int stb[8];
#pragma unroll
  for (int j = 0; j < 8; ++j)
    stb[j] = w * 1024 + j * 128 + (innerL ^ (j << 4));

  // K staging: thread handles LDS slot t (dest base w*1024, lane*16 implied)
  const int krow = w * 8 + (l >> 3);
  const int kseg = (l & 7) ^ (krow & 7);
  const bf16* kP = K + base + (size_t)krow * HD + kseg * 8;
  const bf16* vP = Vh + (size_t)l * HD + w * 8;

  f32x4 yacc[4] = {};
  float m_ = -1e30f, l_ = 0.f;
  const int nt = 2 * qtile + 2;
  const int it_mask = 2 * qtile + (w >= 4 ? 1 : 0);
  const int diag = (w & 3) * 16 + q16;

#define STAGE_K(KBUF)                           \
  {                                             \
    gl_lds16(kP, smem + (KBUF) + w * 1024);     \
    kP += 4096;                                 \
  }
#define WRITE_V(VBUF, a0)                               \
  {                                                     \
    _Pragma("unroll") for (int j = 0; j < 8; ++j)       \
      *(bf16*)(smem + (VBUF) + stb[j]) = a0[j];         \
  }
#define COMPUTE(KBUF, VBUF, DOMASK)                                          \
  {                                                                          \
    f32x4 s[4] = {};                                                         \
    __builtin_amdgcn_s_setprio(1);                                           \
    _Pragma("unroll") for (int nj = 0; nj < 4; ++nj) {                       \
      bf16x8 ak0 = *(const bf16x8*)(smem + (KBUF) + qkB0 + nj * 2048);       \
      s[nj] = __builtin_amdgcn_mfma_f32_16x16x32_bf16(ak0, aq[0], s[nj], 0, 0, 0); \
      bf16x8 ak1 = *(const bf16x8*)(smem + (KBUF) + qkB1 + nj * 2048);       \
      s[nj] = __builtin_amdgcn_mfma_f32_16x16x32_bf16(ak1, aq[1], s[nj], 0, 0, 0); \
    }                                                                        \
    __builtin_amdgcn_s_setprio(0);                                           \
    if (DOMASK) {                                                            \
      _Pragma("unroll") for (int nj = 0; nj < 4; ++nj)                       \
        _Pragma("unroll") for (int r = 0; r < 4; ++r)                        \
          if (nj * 16 + g * 4 + r > diag) s[nj][r] = -1e30f;                 \
    }                                                                        \
    float mx = fmaxf(fmaxf(fmaxf(s[0][0], s[0][1]), fmaxf(s[0][2], s[0][3])),\
                     fmaxf(fmaxf(s[1][0], s[1][1]), fmaxf(s[1][2], s[1][3])));\
    mx = fmaxf(mx, fmaxf(fmaxf(fmaxf(s[2][0], s[2][1]), fmaxf(s[2][2], s[2][3])),\
                         fmaxf(fmaxf(s[3][0], s[3][1]), fmaxf(s[3][2], s[3][3]))));\
    mx = fmaxf(mx, __shfl_xor(mx, 16));                                      \
    mx = fmaxf(mx, __shfl_xor(mx, 32));                                      \
    float mn = fmaxf(m_, mx);                                                \
    float fac = __builtin_amdgcn_exp2f(m_ - mn);                             \
    m_ = mn;                                                                 \
    float rs = 0.f;                                                          \
    _Pragma("unroll") for (int nj = 0; nj < 4; ++nj)                         \
      _Pragma("unroll") for (int r = 0; r < 4; ++r) {                        \
        float pv = __builtin_amdgcn_exp2f(s[nj][r] - mn);                    \
        s[nj][r] = pv;                                                       \
        rs += pv;                                                            \
      }                                                                      \
    rs += __shfl_xor(rs, 16);                                                \
    rs += __shfl_xor(rs, 32);                                                \
    l_ = l_ * fac + rs;                                                      \
    _Pragma("unroll") for (int ni = 0; ni < 4; ++ni)                         \
      _Pragma("unroll") for (int r = 0; r < 4; ++r) yacc[ni][r] *= fac;      \
    __builtin_amdgcn_s_setprio(1);                                           \
    _Pragma("unroll") for (int vkc = 0; vkc < 2; ++vkc) {                    \
      bf16x8 pb;                                                             \
      _Pragma("unroll") for (int j = 0; j < 4; ++j) {                        \
        pb[j] = (bf16)s[2 * vkc][j];                                         \
        pb[4 + j] = (bf16)s[2 * vkc + 1][j];                                 \
      }                                                                      \
      int vb = (vkc == 0) ? qkB0 : qkB1;                                     \
      _Pragma("unroll") for (int ni = 0; ni < 4; ++ni) {                     \
        bf16x8 va = *(const bf16x8*)(smem + (VBUF) + vb + ni * 2048);        \
        yacc[ni] = __builtin_amdgcn_mfma_f32_16x16x32_bf16(va, pb, yacc[ni], 0, 0, 0); \
      }                                                                      \
    }                                                                        \
    __builtin_amdgcn_s_setprio(0);                                           \
  }

  // prologue: tile 0 -> bank 0
  STAGE_K(0);
  {
    bf16x8 a0 = *(const bf16x8*)vP;
    vP += 4096;
    WRITE_V(16384, a0);
  }

  int it = 0;
  for (;;) {
    // even phase: compute bank0, prefetch -> bank1
    __syncthreads();
    bool more = (it + 1) < nt;
    bf16x8 a0;
    if (more) {
      STAGE_K(8192);
      a0 = *(const bf16x8*)vP;
      vP += 4096;
    }
    if (it <= it_mask) COMPUTE(0, 16384, it == it_mask);
    if (more) WRITE_V(24576, a0);
    if (++it >= nt) break;

    // odd phase: compute bank1, prefetch -> bank0
    __syncthreads();
    more = (it + 1) < nt;
    if (more) {
      STAGE_K(0);
      a0 = *(const bf16x8*)vP;
      vP += 4096;
    }
    if (it <= it_mask) COMPUTE(8192, 24576, it == it_mask);
    if (more) WRITE_V(16384, a0);
    if (++it >= nt) break;
  }
#undef STAGE_K
#undef WRITE_V
#undef COMPUTE

  // epilogue: lane owns q = qg; d = ni*16 + g*4 + r (contiguous in r)
  const int hh = bh & 15, bb = bh >> 4;
  float inv = 1.f / l_;
#pragma unroll
  for (int ni = 0; ni < 4; ++ni) {
    bf16x4 o;
#pragma unroll
    for (int r = 0; r < 4; ++r) o[r] = (bf16)(yacc[ni][r] * inv);
    int d0 = ni * 16 + g * 4;
    *(bf16x4*)&Y[(size_t)(bb * Tn + qg) * Cn + hh * HD + d0] = o;
  }
}

extern "C" void kernel_launch(void* const* d_in, const int* in_sizes, int n_in,
                              void* d_out, int out_size, void* d_ws,
                              size_t ws_size, hipStream_t stream) {
  const float* x  = (const float*)d_in[0];
  const float* Wq = (const float*)d_in[1];
  const float* bq = (const float*)d_in[2];
  const float* Wk = (const float*)d_in[3];
  const float* bk = (const float*)d_in[4];
  const float* Wv = (const float*)d_in[5];
  const float* bv = (const float*)d_in[6];
  const float* Wo = (const float*)d_in[7];
  const float* bo = (const float*)d_in[8];
  char* ws = (char*)d_ws;
  bf16* xb = (bf16*)ws;                          // 16MB, reused as y
  bf16* WT = (bf16*)(ws + (size_t)(16 << 20));   // 8MB (4 x 1M elems)
  bf16* Qh = (bf16*)(ws + (size_t)(24 << 20));   // 16MB (K,V follow)
  bf16* Kh = (bf16*)(ws + (size_t)(40 << 20));
  bf16* Vh = (bf16*)(ws + (size_t)(56 << 20));
  float* out = (float*)d_out;                    // reference output is fp32

  const float QSCALE = 0.125f * 1.44269504088896f;  // 1/sqrt(64) * log2(e)

  k_cvt_x<<<4096, 256, 0, stream>>>(x, xb);
  k_tw<<<dim3(32, 32, 4), 256, 0, stream>>>(Wq, Wk, Wv, Wo, WT);
  k_gemm_qkv<<<1536, 256, 0, stream>>>(xb, WT, bq, bk, bv, Qh, QSCALE);
  k_attn<<<1024, 512, 0, stream>>>(Qh, Kh, Vh, xb);
  k_gemm_o<<<512, 256, 0, stream>>>(xb, WT + (3u << 20), bo, out);
}

// Round 12
// 158.256 us; speedup vs baseline: 1.3044x; 1.0200x over previous
//
#include <hip/hip_runtime.h>
#include <hip/hip_bf16.h>
#include <stdint.h>

typedef __bf16 bf16;
typedef __attribute__((ext_vector_type(8))) __bf16 bf16x8;
typedef __attribute__((ext_vector_type(4))) __bf16 bf16x4;
typedef __attribute__((ext_vector_type(4))) float f32x4;

constexpr int Bn = 4, Tn = 2048, Cn = 1024, Hn = 16, HD = 64;
constexpr int Mn = Bn * Tn; // 8192

__device__ __forceinline__ void gl_lds16(const void* g, void* l) {
  __builtin_amdgcn_global_load_lds(
      (const __attribute__((address_space(1))) void*)g,
      (__attribute__((address_space(3))) void*)l, 16u, 0, 0u);
}

// ---------------- x (fp32) -> bf16 ----------------
__global__ __launch_bounds__(256) void k_cvt_x(const float* __restrict__ x,
                                               bf16* __restrict__ xb) {
  int i = (blockIdx.x * 256 + threadIdx.x) * 8;
  float4 a = *(const float4*)(x + i);
  float4 b = *(const float4*)(x + i + 4);
  bf16x8 v;
  v[0] = (bf16)a.x; v[1] = (bf16)a.y; v[2] = (bf16)a.z; v[3] = (bf16)a.w;
  v[4] = (bf16)b.x; v[5] = (bf16)b.y; v[6] = (bf16)b.z; v[7] = (bf16)b.w;
  *(bf16x8*)(xb + i) = v;
}

// ---------------- W [K][N] fp32 -> WT [N][K] bf16 ----------------
__global__ __launch_bounds__(256) void k_tw(const float* __restrict__ W0,
                                            const float* __restrict__ W1,
                                            const float* __restrict__ W2,
                                            const float* __restrict__ W3,
                                            bf16* __restrict__ WT) {
  __shared__ float tile[32][33];
  const float* W = (blockIdx.z == 0) ? W0 : (blockIdx.z == 1) ? W1
                  : (blockIdx.z == 2) ? W2 : W3;
  bf16* out = WT + (size_t)blockIdx.z * Cn * Cn;
  int tx = threadIdx.x & 31, ty = threadIdx.x >> 5;  // 32 x 8
  int gx = blockIdx.x * 32 + tx;   // n
  int gy = blockIdx.y * 32;        // k
#pragma unroll
  for (int j = 0; j < 32; j += 8)
    tile[ty + j][tx] = W[(size_t)(gy + ty + j) * Cn + gx];
  __syncthreads();
  int ox = blockIdx.y * 32 + tx;   // k
  int oy = blockIdx.x * 32;        // n
#pragma unroll
  for (int j = 0; j < 32; j += 8)
    out[(size_t)(oy + ty + j) * Cn + ox] = (bf16)tile[tx][ty + j];
}

// -------- fused QKV GEMM, 256x256 tile, 8-phase counted-vmcnt schedule -----
// N = 3072 (Wq|Wk|Wv stacked). 512 threads = 8 waves (2M x 4N); per-wave
// C = 128x64 = 8mi x 4ni fragments. BK=64, 16 K-tiles. LDS 128 KiB:
// bank(j&1)*65536 + {A-half h: h*16384} {B-half h: 32768 + h*16384}.
// While computing tile j (4 phases x 16 MFMA, per-phase s_barrier+setprio),
// stage ONE half of tile j+1 per phase into the other bank (race-free: that
// bank was last read at tile j-1). One vmcnt(2) per K-tile (counted, never 0
// mid-loop). B-frags read once per tile; A-quads read one phase ahead;
// compiler's own counted lgkmcnt handles ds_read->MFMA.
__global__ __launch_bounds__(512, 2) void k_gemm_qkv8(
    const bf16* __restrict__ A, const bf16* __restrict__ BT,
    const float* __restrict__ bq, const float* __restrict__ bk,
    const float* __restrict__ bv, bf16* __restrict__ out, float qscale) {
  __shared__ __align__(16) char sm[131072];
  const int t = threadIdx.x, w = t >> 6, l = t & 63;
  const int g = l >> 4, q16 = l & 15;
  const int wm = w >> 2, wn = w & 3;
  const int b = blockIdx.x;
  const int k8 = b & 7, idx = b >> 3;  // XCD k8 owns 3 n-cols x 16 m-rows
  const int n0 = ((k8 & 3) * 3 + idx % 3) * 256;
  const int m0 = (idx / 3 + (k8 >> 2) * 16) * 256;

  // LDS read bases (identical swizzle algebra to the proven 128^2 kernel)
  const int xm = (q16 & 7) << 4;
  const int qkB0 = q16 * 128 + ((g * 16) ^ xm);
  const int qkB1 = q16 * 128 + ((64 + g * 16) ^ xm);
  const int aB = wm * 16384;
  const int bB = 32768 + (wn >> 1) * 16384 + (wn & 1) * 8192;

  // staging: thread t covers chunks c = i*512+t of each 16KB half (i=0,1)
  const int row0 = t >> 3;             // [0,64)
  const int row1 = row0 + 64;          // [64,128)
  const int seg = (t & 7) ^ (row0 & 7);  // row1&7 == row0&7
  const bf16* aS0 = A + (size_t)(m0 + row0) * 1024 + seg * 8;
  const bf16* aS1 = A + (size_t)(m0 + row1) * 1024 + seg * 8;
  const bf16* bS0 = BT + (size_t)(n0 + row0) * 1024 + seg * 8;
  const bf16* bS1 = BT + (size_t)(n0 + row1) * 1024 + seg * 8;

  f32x4 acc[8][4] = {};

#define QSTG_A(NB, H, J)                                                  \
  gl_lds16(aS0 + (H) * 131072 + (J) * 64, sm + (NB) + (H) * 16384 + w * 1024); \
  gl_lds16(aS1 + (H) * 131072 + (J) * 64,                                 \
           sm + (NB) + (H) * 16384 + 8192 + w * 1024);
#define QSTG_B(NB, H, J)                                                  \
  gl_lds16(bS0 + (H) * 131072 + (J) * 64,                                 \
           sm + (NB) + 32768 + (H) * 16384 + w * 1024);                   \
  gl_lds16(bS1 + (H) * 131072 + (J) * 64,                                 \
           sm + (NB) + 32768 + (H) * 16384 + 8192 + w * 1024);
#define QRD_A(DST, BANK, MI)                                              \
  DST[0] = *(const bf16x8*)(sm + (BANK) + aB + (MI) * 2048 + qkB0);       \
  DST[1] = *(const bf16x8*)(sm + (BANK) + aB + (MI) * 2048 + qkB1);
#define QMFMA(AF, MI)                                                     \
  _Pragma("unroll") for (int ni = 0; ni < 4; ++ni) {                      \
    acc[MI][ni] = __builtin_amdgcn_mfma_f32_16x16x32_bf16(                \
        AF[0], bfr[ni][0], acc[MI][ni], 0, 0, 0);                         \
    acc[MI][ni] = __builtin_amdgcn_mfma_f32_16x16x32_bf16(                \
        AF[1], bfr[ni][1], acc[MI][ni], 0, 0, 0);                         \
  }

  // prologue: stage K-tile 0 into bank 0 (8 gl_lds, no wait yet)
  QSTG_A(0, 0, 0); QSTG_A(0, 1, 0); QSTG_B(0, 0, 0); QSTG_B(0, 1, 0);

#pragma unroll
  for (int j = 0; j < 16; ++j) {
    const int BANK = (j & 1) ? 65536 : 0;
    const int NB = (j & 1) ? 0 : 65536;
    const bool more = j < 15;
    // ---- phase 0: stage A0(j+1); tile-ready wait; B-all + quad0/1 reads
    if (more) { QSTG_A(NB, 0, j + 1); }
    if (more) asm volatile("s_waitcnt vmcnt(2)" ::: "memory");
    else      asm volatile("s_waitcnt vmcnt(0)" ::: "memory");
    __builtin_amdgcn_sched_barrier(0);
    __builtin_amdgcn_s_barrier();
    __builtin_amdgcn_sched_barrier(0);
    bf16x8 bfr[4][2];
#pragma unroll
    for (int ni = 0; ni < 4; ++ni) {
      bfr[ni][0] = *(const bf16x8*)(sm + BANK + bB + ni * 2048 + qkB0);
      bfr[ni][1] = *(const bf16x8*)(sm + BANK + bB + ni * 2048 + qkB1);
    }
    bf16x8 a0[2], a1[2], a2[2], a3[2];
    QRD_A(a0, BANK, 0); QRD_A(a1, BANK, 1);
    __builtin_amdgcn_s_setprio(1);
    QMFMA(a0, 0); QMFMA(a1, 1);
    __builtin_amdgcn_s_setprio(0);
    __builtin_amdgcn_s_barrier();
    // ---- phase 1: stage A1(j+1); quad2 reads ahead; MFMA quad1? (quads
    // 2,3 of this tile: mi 2,3)
    if (more) { QSTG_A(NB, 1, j + 1); }
    QRD_A(a2, BANK, 2); QRD_A(a3, BANK, 3);
    __builtin_amdgcn_s_setprio(1);
    QMFMA(a2, 2); QMFMA(a3, 3);
    __builtin_amdgcn_s_setprio(0);
    __builtin_amdgcn_s_barrier();
    // ---- phase 2: stage B0(j+1); mi 4,5
    if (more) { QSTG_B(NB, 0, j + 1); }
    QRD_A(a0, BANK, 4); QRD_A(a1, BANK, 5);
    __builtin_amdgcn_s_setprio(1);
    QMFMA(a0, 4); QMFMA(a1, 5);
    __builtin_amdgcn_s_setprio(0);
    __builtin_amdgcn_s_barrier();
    // ---- phase 3: stage B1(j+1); mi 6,7
    if (more) { QSTG_B(NB, 1, j + 1); }
    QRD_A(a2, BANK, 6); QRD_A(a3, BANK, 7);
    __builtin_amdgcn_s_setprio(1);
    QMFMA(a2, 6); QMFMA(a3, 7);
    __builtin_amdgcn_s_setprio(0);
    __builtin_amdgcn_s_barrier();
  }
#undef QSTG_A
#undef QSTG_B
#undef QRD_A
#undef QMFMA

  // epilogue: row = m0 + wm*128 + mi*16 + g*4 + r; col = n0 + wn*64 + ni*16 + q16
#pragma unroll
  for (int ni = 0; ni < 4; ++ni) {
    int colBase = n0 + wn * 64 + ni * 16;
    int which = colBase >> 10;  // 0=Q 1=K 2=V
    const float* bp = (which == 0) ? bq : (which == 1) ? bk : bv;
    float scl = (which == 0) ? qscale : 1.0f;
    float bval = bp[(colBase & 1023) + q16];
    int hh = (colBase >> 6) & 15;
    int dd = (colBase & 63) + q16;
    size_t obase = (size_t)which * 8388608 + (size_t)hh * (Tn * HD) + dd;
#pragma unroll
    for (int mi = 0; mi < 8; ++mi) {
#pragma unroll
      for (int r = 0; r < 4; ++r) {
        int row = m0 + wm * 128 + mi * 16 + g * 4 + r;
        int bb = row >> 11, tt = row & 2047;
        out[obase + ((size_t)bb * Hn * Tn + tt) * HD] =
            (bf16)((acc[mi][ni][r] + bval) * scl);
      }
    }
  }
}

// ---------------- output projection GEMM: out fp32 flat [M][C] ----------
__global__ __launch_bounds__(256) void k_gemm_o(const bf16* __restrict__ A,
                                                const bf16* __restrict__ BT,
                                                const float* __restrict__ bias,
                                                float* __restrict__ out) {
  constexpr int KD = 1024;
  __shared__ __align__(16) bf16 As[128 * 64];
  __shared__ __align__(16) bf16 Bs[128 * 64];
  const int t = threadIdx.x;
  const int w = t >> 6, l = t & 63;
  const int b = blockIdx.x;
  const int m0 = (b >> 3) * 128, n0 = (b & 7) * 128;
  const int wr = (w >> 1) * 64, wc = (w & 1) * 64;
  f32x4 acc[4][4] = {};

  for (int kt = 0; kt < KD; kt += 64) {
    __syncthreads();
#pragma unroll
    for (int i = 0; i < 4; ++i) {
      int c = i * 256 + t;
      int row = c >> 3;
      int seg = (c & 7) ^ (row & 7);
      gl_lds16(A + (size_t)(m0 + row) * KD + kt + seg * 8,
               (char*)As + i * 4096 + w * 1024);
      gl_lds16(BT + (size_t)(n0 + row) * KD + kt + seg * 8,
               (char*)Bs + i * 4096 + w * 1024);
    }
    __syncthreads();
#pragma unroll
    for (int kc = 0; kc < 2; ++kc) {
      bf16x8 af[4], bg[4];
#pragma unroll
      for (int mi = 0; mi < 4; ++mi) {
        int row = wr + mi * 16 + (l & 15);
        int off = (row * 128 + kc * 64 + (l >> 4) * 16) ^ ((row & 7) << 4);
        af[mi] = *(const bf16x8*)((const char*)As + off);
      }
#pragma unroll
      for (int ni = 0; ni < 4; ++ni) {
        int row = wc + ni * 16 + (l & 15);
        int off = (row * 128 + kc * 64 + (l >> 4) * 16) ^ ((row & 7) << 4);
        bg[ni] = *(const bf16x8*)((const char*)Bs + off);
      }
#pragma unroll
      for (int mi = 0; mi < 4; ++mi)
#pragma unroll
        for (int ni = 0; ni < 4; ++ni)
          acc[mi][ni] = __builtin_amdgcn_mfma_f32_16x16x32_bf16(
              af[mi], bg[ni], acc[mi][ni], 0, 0, 0);
    }
  }
#pragma unroll
  for (int ni = 0; ni < 4; ++ni) {
    int col = n0 + wc + ni * 16 + (l & 15);
    float bv = bias[col];
#pragma unroll
    for (int mi = 0; mi < 4; ++mi) {
#pragma unroll
      for (int r = 0; r < 4; ++r) {
        int row = m0 + wr + mi * 16 + (l >> 4) * 4 + r;
        out[(size_t)row * Cn + col] = acc[mi][ni][r] + bv;
      }
    }
  }
}

// ---------------- flash attention (causal), 8-wave QBLK=128 ----------------
__global__ __launch_bounds__(512, 4) void k_attn(const bf16* __restrict__ Q,
                                                 const bf16* __restrict__ K,
                                                 const bf16* __restrict__ V,
                                                 bf16* __restrict__ Y) {
  __shared__ __align__(16) char smem[32768];
  const int t = threadIdx.x, w = t >> 6, l = t & 63;
  const int g = l >> 4, q16 = l & 15;
  const int wg = blockIdx.x;
  const int bh = wg & 63;                      // low bits -> XCD pinning
  const int qtile = 15 - (wg >> 6);            // heavy tiles first
  const size_t base = (size_t)bh * Tn * HD;
  const bf16* Qh = Q + base;
  const bf16* Vh = V + base;
  const int qg = qtile * 128 + w * 16 + q16;   // this lane's q row

  bf16x8 aq[2];
#pragma unroll
  for (int kc = 0; kc < 2; ++kc)
    aq[kc] = *(const bf16x8*)(Qh + (size_t)qg * HD + kc * 32 + g * 8);

  const int xm = (q16 & 7) << 4;
  const int qkB0 = q16 * 128 + ((g * 16) ^ xm);
  const int qkB1 = q16 * 128 + ((64 + g * 16) ^ xm);
  const int innerL = (l >> 5) * 64 + ((l & 15) >> 2) * 16 +
                     (((l >> 4) & 1) * 4 + (l & 3)) * 2;
  int stb[8];
#pragma unroll
  for (int j = 0; j < 8; ++j)
    stb[j] = w * 1024 + j * 128 + (innerL ^ (j << 4));

  const int krow = w * 8 + (l >> 3);
  const int kseg = (l & 7) ^ (krow & 7);
  const bf16* kP = K + base + (size_t)krow * HD + kseg * 8;
  const bf16* vP = Vh + (size_t)l * HD + w * 8;

  f32x4 yacc[4] = {};
  float m_ = -1e30f, l_ = 0.f;
  const int nt = 2 * qtile + 2;
  const int it_mask = 2 * qtile + (w >= 4 ? 1 : 0);
  const int diag = (w & 3) * 16 + q16;

#define STAGE_K(KBUF)                           \
  {                                             \
    gl_lds16(kP, smem + (KBUF) + w * 1024);     \
    kP += 4096;                                 \
  }
#define WRITE_V(VBUF, a0)                               \
  {                                                     \
    _Pragma("unroll") for (int j = 0; j < 8; ++j)       \
      *(bf16*)(smem + (VBUF) + stb[j]) = a0[j];         \
  }
#define COMPUTE(KBUF, VBUF, DOMASK)                                          \
  {                                                                          \
    f32x4 s[4] = {};                                                         \
    __builtin_amdgcn_s_setprio(1);                                           \
    _Pragma("unroll") for (int nj = 0; nj < 4; ++nj) {                       \
      bf16x8 ak0 = *(const bf16x8*)(smem + (KBUF) + qkB0 + nj * 2048);       \
      s[nj] = __builtin_amdgcn_mfma_f32_16x16x32_bf16(ak0, aq[0], s[nj], 0, 0, 0); \
      bf16x8 ak1 = *(const bf16x8*)(smem + (KBUF) + qkB1 + nj * 2048);       \
      s[nj] = __builtin_amdgcn_mfma_f32_16x16x32_bf16(ak1, aq[1], s[nj], 0, 0, 0); \
    }                                                                        \
    __builtin_amdgcn_s_setprio(0);                                           \
    if (DOMASK) {                                                            \
      _Pragma("unroll") for (int nj = 0; nj < 4; ++nj)                       \
        _Pragma("unroll") for (int r = 0; r < 4; ++r)                        \
          if (nj * 16 + g * 4 + r > diag) s[nj][r] = -1e30f;                 \
    }                                                                        \
    float mx = fmaxf(fmaxf(fmaxf(s[0][0], s[0][1]), fmaxf(s[0][2], s[0][3])),\
                     fmaxf(fmaxf(s[1][0], s[1][1]), fmaxf(s[1][2], s[1][3])));\
    mx = fmaxf(mx, fmaxf(fmaxf(fmaxf(s[2][0], s[2][1]), fmaxf(s[2][2], s[2][3])),\
                         fmaxf(fmaxf(s[3][0], s[3][1]), fmaxf(s[3][2], s[3][3]))));\
    mx = fmaxf(mx, __shfl_xor(mx, 16));                                      \
    mx = fmaxf(mx, __shfl_xor(mx, 32));                                      \
    float mn = fmaxf(m_, mx);                                                \
    float fac = __builtin_amdgcn_exp2f(m_ - mn);                             \
    m_ = mn;                                                                 \
    float rs = 0.f;                                                          \
    _Pragma("unroll") for (int nj = 0; nj < 4; ++nj)                         \
      _Pragma("unroll") for (int r = 0; r < 4; ++r) {                        \
        float pv = __builtin_amdgcn_exp2f(s[nj][r] - mn);                    \
        s[nj][r] = pv;                                                       \
        rs += pv;                                                            \
      }                                                                      \
    rs += __shfl_xor(rs, 16);                                                \
    rs += __shfl_xor(rs, 32);                                                \
    l_ = l_ * fac + rs;                                                      \
    _Pragma("unroll") for (int ni = 0; ni < 4; ++ni)                         \
      _Pragma("unroll") for (int r = 0; r < 4; ++r) yacc[ni][r] *= fac;      \
    __builtin_amdgcn_s_setprio(1);                                           \
    _Pragma("unroll") for (int vkc = 0; vkc < 2; ++vkc) {                    \
      bf16x8 pb;                                                             \
      _Pragma("unroll") for (int j = 0; j < 4; ++j) {                        \
        pb[j] = (bf16)s[2 * vkc][j];                                         \
        pb[4 + j] = (bf16)s[2 * vkc + 1][j];                                 \
      }                                                                      \
      int vb = (vkc == 0) ? qkB0 : qkB1;                                     \
      _Pragma("unroll") for (int ni = 0; ni < 4; ++ni) {                     \
        bf16x8 va = *(const bf16x8*)(smem + (VBUF) + vb + ni * 2048);        \
        yacc[ni] = __builtin_amdgcn_mfma_f32_16x16x32_bf16(va, pb, yacc[ni], 0, 0, 0); \
      }                                                                      \
    }                                                                        \
    __builtin_amdgcn_s_setprio(0);                                           \
  }

  STAGE_K(0);
  {
    bf16x8 a0 = *(const bf16x8*)vP;
    vP += 4096;
    WRITE_V(16384, a0);
  }

  int it = 0;
  for (;;) {
    __syncthreads();
    bool more = (it + 1) < nt;
    bf16x8 a0;
    if (more) {
      STAGE_K(8192);
      a0 = *(const bf16x8*)vP;
      vP += 4096;
    }
    if (it <= it_mask) COMPUTE(0, 16384, it == it_mask);
    if (more) WRITE_V(24576, a0);
    if (++it >= nt) break;

    __syncthreads();
    more = (it + 1) < nt;
    if (more) {
      STAGE_K(0);
      a0 = *(const bf16x8*)vP;
      vP += 4096;
    }
    if (it <= it_mask) COMPUTE(8192, 24576, it == it_mask);
    if (more) WRITE_V(16384, a0);
    if (++it >= nt) break;
  }
#undef STAGE_K
#undef WRITE_V
#undef COMPUTE

  const int hh = bh & 15, bb = bh >> 4;
  float inv = 1.f / l_;
#pragma unroll
  for (int ni = 0; ni < 4; ++ni) {
    bf16x4 o;
#pragma unroll
    for (int r = 0; r < 4; ++r) o[r] = (bf16)(yacc[ni][r] * inv);
    int d0 = ni * 16 + g * 4;
    *(bf16x4*)&Y[(size_t)(bb * Tn + qg) * Cn + hh * HD + d0] = o;
  }
}

extern "C" void kernel_launch(void* const* d_in, const int* in_sizes, int n_in,
                              void* d_out, int out_size, void* d_ws,
                              size_t ws_size, hipStream_t stream) {
  const float* x  = (const float*)d_in[0];
  const float* Wq = (const float*)d_in[1];
  const float* bq = (const float*)d_in[2];
  const float* Wk = (const float*)d_in[3];
  const float* bk = (const float*)d_in[4];
  const float* Wv = (const float*)d_in[5];
  const float* bv = (const float*)d_in[6];
  const float* Wo = (const float*)d_in[7];
  const float* bo = (const float*)d_in[8];
  char* ws = (char*)d_ws;
  bf16* xb = (bf16*)ws;                          // 16MB, reused as y
  bf16* WT = (bf16*)(ws + (size_t)(16 << 20));   // 8MB (4 x 1M elems)
  bf16* Qh = (bf16*)(ws + (size_t)(24 << 20));   // 16MB (K,V follow)
  bf16* Kh = (bf16*)(ws + (size_t)(40 << 20));
  bf16* Vh = (bf16*)(ws + (size_t)(56 << 20));
  float* out = (float*)d_out;                    // reference output is fp32

  const float QSCALE = 0.125f * 1.44269504088896f;  // 1/sqrt(64) * log2(e)

  k_cvt_x<<<4096, 256, 0, stream>>>(x, xb);
  k_tw<<<dim3(32, 32, 4), 256, 0, stream>>>(Wq, Wk, Wv, Wo, WT);
  k_gemm_qkv8<<<384, 512, 0, stream>>>(xb, WT, bq, bk, bv, Qh, QSCALE);
  k_attn<<<1024, 512, 0, stream>>>(Qh, Kh, Vh, xb);
  k_gemm_o<<<512, 256, 0, stream>>>(xb, WT + (3u << 20), bo, out);
}

// Round 13
// 155.656 us; speedup vs baseline: 1.3262x; 1.0167x over previous
//
#include <hip/hip_runtime.h>
#include <hip/hip_bf16.h>
#include <stdint.h>

typedef __bf16 bf16;
typedef __attribute__((ext_vector_type(8))) __bf16 bf16x8;
typedef __attribute__((ext_vector_type(4))) __bf16 bf16x4;
typedef __attribute__((ext_vector_type(4))) float f32x4;

constexpr int Bn = 4, Tn = 2048, Cn = 1024, Hn = 16, HD = 64;
constexpr int Mn = Bn * Tn; // 8192

__device__ __forceinline__ void gl_lds16(const void* g, void* l) {
  __builtin_amdgcn_global_load_lds(
      (const __attribute__((address_space(1))) void*)g,
      (__attribute__((address_space(3))) void*)l, 16u, 0, 0u);
}

// ---------------- x (fp32) -> bf16 ----------------
__global__ __launch_bounds__(256) void k_cvt_x(const float* __restrict__ x,
                                               bf16* __restrict__ xb) {
  int i = (blockIdx.x * 256 + threadIdx.x) * 8;
  float4 a = *(const float4*)(x + i);
  float4 b = *(const float4*)(x + i + 4);
  bf16x8 v;
  v[0] = (bf16)a.x; v[1] = (bf16)a.y; v[2] = (bf16)a.z; v[3] = (bf16)a.w;
  v[4] = (bf16)b.x; v[5] = (bf16)b.y; v[6] = (bf16)b.z; v[7] = (bf16)b.w;
  *(bf16x8*)(xb + i) = v;
}

// ---------------- W [K][N] fp32 -> WT [N][K] bf16 ----------------
__global__ __launch_bounds__(256) void k_tw(const float* __restrict__ W0,
                                            const float* __restrict__ W1,
                                            const float* __restrict__ W2,
                                            const float* __restrict__ W3,
                                            bf16* __restrict__ WT) {
  __shared__ float tile[32][33];
  const float* W = (blockIdx.z == 0) ? W0 : (blockIdx.z == 1) ? W1
                  : (blockIdx.z == 2) ? W2 : W3;
  bf16* out = WT + (size_t)blockIdx.z * Cn * Cn;
  int tx = threadIdx.x & 31, ty = threadIdx.x >> 5;  // 32 x 8
  int gx = blockIdx.x * 32 + tx;   // n
  int gy = blockIdx.y * 32;        // k
#pragma unroll
  for (int j = 0; j < 32; j += 8)
    tile[ty + j][tx] = W[(size_t)(gy + ty + j) * Cn + gx];
  __syncthreads();
  int ox = blockIdx.y * 32 + tx;   // k
  int oy = blockIdx.x * 32;        // n
#pragma unroll
  for (int j = 0; j < 32; j += 8)
    out[(size_t)(oy + ty + j) * Cn + ox] = (bf16)tile[tx][ty + j];
}

// -------- fused QKV GEMM, 128x256 tile, counted-vmcnt 2-phase schedule -----
// N = 3072. 768 blocks = 64 m-tiles x 12 n-tiles = EXACTLY 3 rounds of 256
// CUs (zero tail). 512 threads = 8 waves (2M x 4N), per-wave C = 64x64
// (acc[4][4] = 64 f32 -- the proven register budget; round-12's 128-f32 acc
// spilled 35 MB). LDS 96 KiB dbuf: bank(j&1)*49152 + {A 16K @0, B 32K @16384}.
// Per K-tile (BK=64): P0 {stage A+Bh0 of j+1 (4 gl_lds); vmcnt(4); barrier;
// read B-all(8)+A mi0,1(4); 32 MFMA} P1 {stage Bh1 (2); read A mi2,3; 32
// MFMA; barrier}. Counted vmcnt only -- never 0 mid-loop. Race-safe: NB was
// last read in tile j-1 whose reads complete before its trailing barrier.
__global__ __launch_bounds__(512, 2) void k_gemm_qkv8(
    const bf16* __restrict__ A, const bf16* __restrict__ BT,
    const float* __restrict__ bq, const float* __restrict__ bk,
    const float* __restrict__ bv, bf16* __restrict__ out, float qscale) {
  __shared__ __align__(16) char sm[98304];
  const int t = threadIdx.x, w = t >> 6, l = t & 63;
  const int g = l >> 4, q16 = l & 15;
  const int wm = w >> 2, wn = w & 3;
  const int b = blockIdx.x;
  const int m0 = (b / 12) * 128, n0 = (b % 12) * 256;

  const int xm = (q16 & 7) << 4;
  const int qkB0 = q16 * 128 + ((g * 16) ^ xm);
  const int qkB1 = q16 * 128 + ((64 + g * 16) ^ xm);

  // staging source pointers (row = c*64 + (t>>3), seg inverse-swizzled)
  const int srow = t >> 3;
  const int sseg = (t & 7) ^ (srow & 7);
  const bf16* aP0 = A + (size_t)(m0 + srow) * 1024 + sseg * 8;
  const bf16* aP1 = aP0 + 65536;            // +64 rows
  const bf16* bP0 = BT + (size_t)(n0 + srow) * 1024 + sseg * 8;
  const bf16* bP1 = bP0 + 65536;
  const bf16* bP2 = bP0 + 131072;
  const bf16* bP3 = bP0 + 196608;

  f32x4 acc[4][4] = {};

#define STG_A(BK_, J)                                        \
  gl_lds16(aP0 + (J) * 64, sm + (BK_) + w * 1024);           \
  gl_lds16(aP1 + (J) * 64, sm + (BK_) + 8192 + w * 1024);
#define STG_B0(BK_, J)                                       \
  gl_lds16(bP0 + (J) * 64, sm + (BK_) + 16384 + w * 1024);   \
  gl_lds16(bP1 + (J) * 64, sm + (BK_) + 24576 + w * 1024);
#define STG_B1(BK_, J)                                       \
  gl_lds16(bP2 + (J) * 64, sm + (BK_) + 32768 + w * 1024);   \
  gl_lds16(bP3 + (J) * 64, sm + (BK_) + 40960 + w * 1024);
#define RD_A(DST, BK_, MI)                                                  \
  DST[0] = *(const bf16x8*)(sm + (BK_) + wm * 8192 + (MI) * 2048 + qkB0);   \
  DST[1] = *(const bf16x8*)(sm + (BK_) + wm * 8192 + (MI) * 2048 + qkB1);
#define RD_B(DST, BK_, NI)                                                  \
  DST[0] = *(const bf16x8*)(sm + (BK_) + 16384 + wn * 8192 + (NI) * 2048 + qkB0); \
  DST[1] = *(const bf16x8*)(sm + (BK_) + 16384 + wn * 8192 + (NI) * 2048 + qkB1);
#define MFMA_MI(MI, AF)                                                     \
  _Pragma("unroll") for (int ni = 0; ni < 4; ++ni) {                        \
    acc[MI][ni] = __builtin_amdgcn_mfma_f32_16x16x32_bf16(                  \
        AF[0], bfr[ni][0], acc[MI][ni], 0, 0, 0);                           \
    acc[MI][ni] = __builtin_amdgcn_mfma_f32_16x16x32_bf16(                  \
        AF[1], bfr[ni][1], acc[MI][ni], 0, 0, 0);                           \
  }

  // prologue: tile 0 -> bank 0 (6 loads)
  STG_A(0, 0); STG_B0(0, 0); STG_B1(0, 0);

#pragma unroll
  for (int j = 0; j < 16; ++j) {
    const int BK_ = (j & 1) ? 49152 : 0;
    const int NB_ = 49152 - BK_;
    const bool more = j < 15;
    // ---- phase 0
    if (more) { STG_A(NB_, j + 1); STG_B0(NB_, j + 1); }
    if (more) asm volatile("s_waitcnt vmcnt(4)" ::: "memory");
    else      asm volatile("s_waitcnt vmcnt(0)" ::: "memory");
    __builtin_amdgcn_sched_barrier(0);
    __builtin_amdgcn_s_barrier();
    bf16x8 bfr[4][2];
    RD_B(bfr[0], BK_, 0); RD_B(bfr[1], BK_, 1);
    RD_B(bfr[2], BK_, 2); RD_B(bfr[3], BK_, 3);
    bf16x8 af0[2], af1[2];
    RD_A(af0, BK_, 0); RD_A(af1, BK_, 1);
    __builtin_amdgcn_s_setprio(1);
    MFMA_MI(0, af0); MFMA_MI(1, af1);
    __builtin_amdgcn_s_setprio(0);
    // ---- phase 1
    if (more) { STG_B1(NB_, j + 1); }
    RD_A(af0, BK_, 2); RD_A(af1, BK_, 3);
    __builtin_amdgcn_s_setprio(1);
    MFMA_MI(2, af0); MFMA_MI(3, af1);
    __builtin_amdgcn_s_setprio(0);
    __builtin_amdgcn_s_barrier();  // all reads of bank BK_ consumed
  }
#undef STG_A
#undef STG_B0
#undef STG_B1
#undef RD_A
#undef RD_B
#undef MFMA_MI

  // epilogue: row = m0 + wm*64 + mi*16 + g*4 + r; col = n0 + wn*64 + ni*16 + q16
#pragma unroll
  for (int ni = 0; ni < 4; ++ni) {
    int colBase = n0 + wn * 64 + ni * 16;
    int which = colBase >> 10;  // 0=Q 1=K 2=V
    const float* bp = (which == 0) ? bq : (which == 1) ? bk : bv;
    float scl = (which == 0) ? qscale : 1.0f;
    float bval = bp[(colBase & 1023) + q16];
    int hh = (colBase >> 6) & 15;
    int dd = (colBase & 63) + q16;
    size_t obase = (size_t)which * 8388608 + (size_t)hh * (Tn * HD) + dd;
#pragma unroll
    for (int mi = 0; mi < 4; ++mi) {
#pragma unroll
      for (int r = 0; r < 4; ++r) {
        int row = m0 + wm * 64 + mi * 16 + g * 4 + r;
        int bb = row >> 11, tt = row & 2047;
        out[obase + ((size_t)bb * Hn * Tn + tt) * HD] =
            (bf16)((acc[mi][ni][r] + bval) * scl);
      }
    }
  }
}

// ---------------- output projection GEMM: out fp32 flat [M][C] ----------
__global__ __launch_bounds__(256) void k_gemm_o(const bf16* __restrict__ A,
                                                const bf16* __restrict__ BT,
                                                const float* __restrict__ bias,
                                                float* __restrict__ out) {
  constexpr int KD = 1024;
  __shared__ __align__(16) bf16 As[128 * 64];
  __shared__ __align__(16) bf16 Bs[128 * 64];
  const int t = threadIdx.x;
  const int w = t >> 6, l = t & 63;
  const int b = blockIdx.x;
  const int m0 = (b >> 3) * 128, n0 = (b & 7) * 128;
  const int wr = (w >> 1) * 64, wc = (w & 1) * 64;
  f32x4 acc[4][4] = {};

  for (int kt = 0; kt < KD; kt += 64) {
    __syncthreads();
#pragma unroll
    for (int i = 0; i < 4; ++i) {
      int c = i * 256 + t;
      int row = c >> 3;
      int seg = (c & 7) ^ (row & 7);
      gl_lds16(A + (size_t)(m0 + row) * KD + kt + seg * 8,
               (char*)As + i * 4096 + w * 1024);
      gl_lds16(BT + (size_t)(n0 + row) * KD + kt + seg * 8,
               (char*)Bs + i * 4096 + w * 1024);
    }
    __syncthreads();
#pragma unroll
    for (int kc = 0; kc < 2; ++kc) {
      bf16x8 af[4], bg[4];
#pragma unroll
      for (int mi = 0; mi < 4; ++mi) {
        int row = wr + mi * 16 + (l & 15);
        int off = (row * 128 + kc * 64 + (l >> 4) * 16) ^ ((row & 7) << 4);
        af[mi] = *(const bf16x8*)((const char*)As + off);
      }
#pragma unroll
      for (int ni = 0; ni < 4; ++ni) {
        int row = wc + ni * 16 + (l & 15);
        int off = (row * 128 + kc * 64 + (l >> 4) * 16) ^ ((row & 7) << 4);
        bg[ni] = *(const bf16x8*)((const char*)Bs + off);
      }
#pragma unroll
      for (int mi = 0; mi < 4; ++mi)
#pragma unroll
        for (int ni = 0; ni < 4; ++ni)
          acc[mi][ni] = __builtin_amdgcn_mfma_f32_16x16x32_bf16(
              af[mi], bg[ni], acc[mi][ni], 0, 0, 0);
    }
  }
#pragma unroll
  for (int ni = 0; ni < 4; ++ni) {
    int col = n0 + wc + ni * 16 + (l & 15);
    float bv = bias[col];
#pragma unroll
    for (int mi = 0; mi < 4; ++mi) {
#pragma unroll
      for (int r = 0; r < 4; ++r) {
        int row = m0 + wr + mi * 16 + (l >> 4) * 4 + r;
        out[(size_t)row * Cn + col] = acc[mi][ni][r] + bv;
      }
    }
  }
}

// ---------------- flash attention (causal), 8-wave QBLK=128 ----------------
__global__ __launch_bounds__(512, 4) void k_attn(const bf16* __restrict__ Q,
                                                 const bf16* __restrict__ K,
                                                 const bf16* __restrict__ V,
                                                 bf16* __restrict__ Y) {
  __shared__ __align__(16) char smem[32768];
  const int t = threadIdx.x, w = t >> 6, l = t & 63;
  const int g = l >> 4, q16 = l & 15;
  const int wg = blockIdx.x;
  const int bh = wg & 63;                      // low bits -> XCD pinning
  const int qtile = 15 - (wg >> 6);            // heavy tiles first
  const size_t base = (size_t)bh * Tn * HD;
  const bf16* Qh = Q + base;
  const bf16* Vh = V + base;
  const int qg = qtile * 128 + w * 16 + q16;   // this lane's q row

  bf16x8 aq[2];
#pragma unroll
  for (int kc = 0; kc < 2; ++kc)
    aq[kc] = *(const bf16x8*)(Qh + (size_t)qg * HD + kc * 32 + g * 8);

  const int xm = (q16 & 7) << 4;
  const int qkB0 = q16 * 128 + ((g * 16) ^ xm);
  const int qkB1 = q16 * 128 + ((64 + g * 16) ^ xm);
  const int innerL = (l >> 5) * 64 + ((l & 15) >> 2) * 16 +
                     (((l >> 4) & 1) * 4 + (l & 3)) * 2;
  int stb[8];
#pragma unroll
  for (int j = 0; j < 8; ++j)
    stb[j] = w * 1024 + j * 128 + (innerL ^ (j << 4));

  const int krow = w * 8 + (l >> 3);
  const int kseg = (l & 7) ^ (krow & 7);
  const bf16* kP = K + base + (size_t)krow * HD + kseg * 8;
  const bf16* vP = Vh + (size_t)l * HD + w * 8;

  f32x4 yacc[4] = {};
  float m_ = -1e30f, l_ = 0.f;
  const int nt = 2 * qtile + 2;
  const int it_mask = 2 * qtile + (w >= 4 ? 1 : 0);
  const int diag = (w & 3) * 16 + q16;

#define STAGE_K(KBUF)                           \
  {                                             \
    gl_lds16(kP, smem + (KBUF) + w * 1024);     \
    kP += 4096;                                 \
  }
#define WRITE_V(VBUF, a0)                               \
  {                                                     \
    _Pragma("unroll") for (int j = 0; j < 8; ++j)       \
      *(bf16*)(smem + (VBUF) + stb[j]) = a0[j];         \
  }
#define COMPUTE(KBUF, VBUF, DOMASK)                                          \
  {                                                                          \
    f32x4 s[4] = {};                                                         \
    __builtin_amdgcn_s_setprio(1);                                           \
    _Pragma("unroll") for (int nj = 0; nj < 4; ++nj) {                       \
      bf16x8 ak0 = *(const bf16x8*)(smem + (KBUF) + qkB0 + nj * 2048);       \
      s[nj] = __builtin_amdgcn_mfma_f32_16x16x32_bf16(ak0, aq[0], s[nj], 0, 0, 0); \
      bf16x8 ak1 = *(const bf16x8*)(smem + (KBUF) + qkB1 + nj * 2048);       \
      s[nj] = __builtin_amdgcn_mfma_f32_16x16x32_bf16(ak1, aq[1], s[nj], 0, 0, 0); \
    }                                                                        \
    __builtin_amdgcn_s_setprio(0);                                           \
    if (DOMASK) {                                                            \
      _Pragma("unroll") for (int nj = 0; nj < 4; ++nj)                       \
        _Pragma("unroll") for (int r = 0; r < 4; ++r)                        \
          if (nj * 16 + g * 4 + r > diag) s[nj][r] = -1e30f;                 \
    }                                                                        \
    float mx = fmaxf(fmaxf(fmaxf(s[0][0], s[0][1]), fmaxf(s[0][2], s[0][3])),\
                     fmaxf(fmaxf(s[1][0], s[1][1]), fmaxf(s[1][2], s[1][3])));\
    mx = fmaxf(mx, fmaxf(fmaxf(fmaxf(s[2][0], s[2][1]), fmaxf(s[2][2], s[2][3])),\
                         fmaxf(fmaxf(s[3][0], s[3][1]), fmaxf(s[3][2], s[3][3]))));\
    mx = fmaxf(mx, __shfl_xor(mx, 16));                                      \
    mx = fmaxf(mx, __shfl_xor(mx, 32));                                      \
    float mn = fmaxf(m_, mx);                                                \
    float fac = __builtin_amdgcn_exp2f(m_ - mn);                             \
    m_ = mn;                                                                 \
    float rs = 0.f;                                                          \
    _Pragma("unroll") for (int nj = 0; nj < 4; ++nj)                         \
      _Pragma("unroll") for (int r = 0; r < 4; ++r) {                        \
        float pv = __builtin_amdgcn_exp2f(s[nj][r] - mn);                    \
        s[nj][r] = pv;                                                       \
        rs += pv;                                                            \
      }                                                                      \
    rs += __shfl_xor(rs, 16);                                                \
    rs += __shfl_xor(rs, 32);                                                \
    l_ = l_ * fac + rs;                                                      \
    _Pragma("unroll") for (int ni = 0; ni < 4; ++ni)                         \
      _Pragma("unroll") for (int r = 0; r < 4; ++r) yacc[ni][r] *= fac;      \
    __builtin_amdgcn_s_setprio(1);                                           \
    _Pragma("unroll") for (int vkc = 0; vkc < 2; ++vkc) {                    \
      bf16x8 pb;                                                             \
      _Pragma("unroll") for (int j = 0; j < 4; ++j) {                        \
        pb[j] = (bf16)s[2 * vkc][j];                                         \
        pb[4 + j] = (bf16)s[2 * vkc + 1][j];                                 \
      }                                                                      \
      int vb = (vkc == 0) ? qkB0 : qkB1;                                     \
      _Pragma("unroll") for (int ni = 0; ni < 4; ++ni) {                     \
        bf16x8 va = *(const bf16x8*)(smem + (VBUF) + vb + ni * 2048);        \
        yacc[ni] = __builtin_amdgcn_mfma_f32_16x16x32_bf16(va, pb, yacc[ni], 0, 0, 0); \
      }                                                                      \
    }                                                                        \
    __builtin_amdgcn_s_setprio(0);                                           \
  }

  STAGE_K(0);
  {
    bf16x8 a0 = *(const bf16x8*)vP;
    vP += 4096;
    WRITE_V(16384, a0);
  }

  int it = 0;
  for (;;) {
    __syncthreads();
    bool more = (it + 1) < nt;
    bf16x8 a0;
    if (more) {
      STAGE_K(8192);
      a0 = *(const bf16x8*)vP;
      vP += 4096;
    }
    if (it <= it_mask) COMPUTE(0, 16384, it == it_mask);
    if (more) WRITE_V(24576, a0);
    if (++it >= nt) break;

    __syncthreads();
    more = (it + 1) < nt;
    if (more) {
      STAGE_K(0);
      a0 = *(const bf16x8*)vP;
      vP += 4096;
    }
    if (it <= it_mask) COMPUTE(8192, 24576, it == it_mask);
    if (more) WRITE_V(16384, a0);
    if (++it >= nt) break;
  }
#undef STAGE_K
#undef WRITE_V
#undef COMPUTE

  const int hh = bh & 15, bb = bh >> 4;
  float inv = 1.f / l_;
#pragma unroll
  for (int ni = 0; ni < 4; ++ni) {
    bf16x4 o;
#pragma unroll
    for (int r = 0; r < 4; ++r) o[r] = (bf16)(yacc[ni][r] * inv);
    int d0 = ni * 16 + g * 4;
    *(bf16x4*)&Y[(size_t)(bb * Tn + qg) * Cn + hh * HD + d0] = o;
  }
}

extern "C" void kernel_launch(void* const* d_in, const int* in_sizes, int n_in,
                              void* d_out, int out_size, void* d_ws,
                              size_t ws_size, hipStream_t stream) {
  const float* x  = (const float*)d_in[0];
  const float* Wq = (const float*)d_in[1];
  const float* bq = (const float*)d_in[2];
  const float* Wk = (const float*)d_in[3];
  const float* bk = (const float*)d_in[4];
  const float* Wv = (const float*)d_in[5];
  const float* bv = (const float*)d_in[6];
  const float* Wo = (const float*)d_in[7];
  const float* bo = (const float*)d_in[8];
  char* ws = (char*)d_ws;
  bf16* xb = (bf16*)ws;                          // 16MB, reused as y
  bf16* WT = (bf16*)(ws + (size_t)(16 << 20));   // 8MB (4 x 1M elems)
  bf16* Qh = (bf16*)(ws + (size_t)(24 << 20));   // 16MB (K,V follow)
  bf16* Kh = (bf16*)(ws + (size_t)(40 << 20));
  bf16* Vh = (bf16*)(ws + (size_t)(56 << 20));
  float* out = (float*)d_out;                    // reference output is fp32

  const float QSCALE = 0.125f * 1.44269504088896f;  // 1/sqrt(64) * log2(e)

  k_cvt_x<<<4096, 256, 0, stream>>>(x, xb);
  k_tw<<<dim3(32, 32, 4), 256, 0, stream>>>(Wq, Wk, Wv, Wo, WT);
  k_gemm_qkv8<<<768, 512, 0, stream>>>(xb, WT, bq, bk, bv, Qh, QSCALE);
  k_attn<<<1024, 512, 0, stream>>>(Qh, Kh, Vh, xb);
  k_gemm_o<<<512, 256, 0, stream>>>(xb, WT + (3u << 20), bo, out);
}

// Round 14
// 151.974 us; speedup vs baseline: 1.3583x; 1.0242x over previous
//
#include <hip/hip_runtime.h>
#include <hip/hip_bf16.h>
#include <stdint.h>

typedef __bf16 bf16;
typedef __attribute__((ext_vector_type(8))) __bf16 bf16x8;
typedef __attribute__((ext_vector_type(4))) __bf16 bf16x4;
typedef __attribute__((ext_vector_type(4))) float f32x4;

constexpr int Bn = 4, Tn = 2048, Cn = 1024, Hn = 16, HD = 64;
constexpr int Mn = Bn * Tn; // 8192

__device__ __forceinline__ void gl_lds16(const void* g, void* l) {
  __builtin_amdgcn_global_load_lds(
      (const __attribute__((address_space(1))) void*)g,
      (__attribute__((address_space(3))) void*)l, 16u, 0, 0u);
}

// ---------------- x (fp32) -> bf16 ----------------
__global__ __launch_bounds__(256) void k_cvt_x(const float* __restrict__ x,
                                               bf16* __restrict__ xb) {
  int i = (blockIdx.x * 256 + threadIdx.x) * 8;
  float4 a = *(const float4*)(x + i);
  float4 b = *(const float4*)(x + i + 4);
  bf16x8 v;
  v[0] = (bf16)a.x; v[1] = (bf16)a.y; v[2] = (bf16)a.z; v[3] = (bf16)a.w;
  v[4] = (bf16)b.x; v[5] = (bf16)b.y; v[6] = (bf16)b.z; v[7] = (bf16)b.w;
  *(bf16x8*)(xb + i) = v;
}

// ---------------- W [K][N] fp32 -> WT [N][K] bf16 ----------------
__global__ __launch_bounds__(256) void k_tw(const float* __restrict__ W0,
                                            const float* __restrict__ W1,
                                            const float* __restrict__ W2,
                                            const float* __restrict__ W3,
                                            bf16* __restrict__ WT) {
  __shared__ float tile[32][33];
  const float* W = (blockIdx.z == 0) ? W0 : (blockIdx.z == 1) ? W1
                  : (blockIdx.z == 2) ? W2 : W3;
  bf16* out = WT + (size_t)blockIdx.z * Cn * Cn;
  int tx = threadIdx.x & 31, ty = threadIdx.x >> 5;  // 32 x 8
  int gx = blockIdx.x * 32 + tx;   // n
  int gy = blockIdx.y * 32;        // k
#pragma unroll
  for (int j = 0; j < 32; j += 8)
    tile[ty + j][tx] = W[(size_t)(gy + ty + j) * Cn + gx];
  __syncthreads();
  int ox = blockIdx.y * 32 + tx;   // k
  int oy = blockIdx.x * 32;        // n
#pragma unroll
  for (int j = 0; j < 32; j += 8)
    out[(size_t)(oy + ty + j) * Cn + ox] = (bf16)tile[tx][ty + j];
}

// ---- shared 2-phase counted-vmcnt GEMM core (128x128, BK=64, 8 waves) ----
// 64 KiB LDS (2 blocks/CU -> TLP through barrier stalls). Per-wave 64x32
// (wm in {0,1}, wn in {0..3}), acc[4][2] = 32 f32. Per K-tile: P0 {stage 4
// gl_lds of j+1; vmcnt(4); barrier; read B(4)+A01(4); 8 MFMA} P1 {read A23;
// 8 MFMA; barrier}. Counted vmcnt only; race-safety identical to round-13's
// refcheck-passed schedule (bank last read in tile j-1, reads retired
// before its trailing barrier via compiler lgkmcnt before MFMA).
#define GEMM_CORE(ACC)                                                      \
  const int t = threadIdx.x, l = t & 63, w = t >> 6;                        \
  const int g = l >> 4, q16 = l & 15;                                       \
  const int wm = w >> 2, wn = w & 3;                                        \
  const int xm = (q16 & 7) << 4;                                            \
  const int qkB0 = q16 * 128 + ((g * 16) ^ xm);                             \
  const int qkB1 = q16 * 128 + ((64 + g * 16) ^ xm);                        \
  const int srow = t >> 3;                                                  \
  const int sseg = (t & 7) ^ (srow & 7);                                    \
  const bf16* aP0 = A + (size_t)(m0 + srow) * 1024 + sseg * 8;              \
  const bf16* aP1 = aP0 + 65536;                                            \
  const bf16* bP0 = BT + (size_t)(n0 + srow) * 1024 + sseg * 8;             \
  const bf16* bP1 = bP0 + 65536;                                            \
  f32x4 ACC[4][2] = {};                                                     \
  /* prologue: tile 0 -> bank 0 */                                          \
  gl_lds16(aP0, sm + w * 1024);                                             \
  gl_lds16(aP1, sm + 8192 + w * 1024);                                      \
  gl_lds16(bP0, sm + 16384 + w * 1024);                                     \
  gl_lds16(bP1, sm + 24576 + w * 1024);                                     \
  _Pragma("unroll")                                                         \
  for (int j = 0; j < 16; ++j) {                                            \
    const int BK_ = (j & 1) ? 32768 : 0;                                    \
    const int NB_ = 32768 - BK_;                                            \
    const bool more = j < 15;                                               \
    if (more) {                                                             \
      gl_lds16(aP0 + (j + 1) * 64, sm + NB_ + w * 1024);                    \
      gl_lds16(aP1 + (j + 1) * 64, sm + NB_ + 8192 + w * 1024);             \
      gl_lds16(bP0 + (j + 1) * 64, sm + NB_ + 16384 + w * 1024);            \
      gl_lds16(bP1 + (j + 1) * 64, sm + NB_ + 24576 + w * 1024);            \
      asm volatile("s_waitcnt vmcnt(4)" ::: "memory");                      \
    } else {                                                                \
      asm volatile("s_waitcnt vmcnt(0)" ::: "memory");                      \
    }                                                                       \
    __builtin_amdgcn_sched_barrier(0);                                      \
    __builtin_amdgcn_s_barrier();                                           \
    bf16x8 bfr[2][2], af0[2], af1[2];                                       \
    _Pragma("unroll") for (int ni = 0; ni < 2; ++ni) {                      \
      bfr[ni][0] = *(const bf16x8*)(sm + BK_ + 16384 + wn * 4096 +          \
                                    ni * 2048 + qkB0);                      \
      bfr[ni][1] = *(const bf16x8*)(sm + BK_ + 16384 + wn * 4096 +          \
                                    ni * 2048 + qkB1);                      \
    }                                                                       \
    af0[0] = *(const bf16x8*)(sm + BK_ + wm * 8192 + qkB0);                 \
    af0[1] = *(const bf16x8*)(sm + BK_ + wm * 8192 + qkB1);                 \
    af1[0] = *(const bf16x8*)(sm + BK_ + wm * 8192 + 2048 + qkB0);          \
    af1[1] = *(const bf16x8*)(sm + BK_ + wm * 8192 + 2048 + qkB1);          \
    __builtin_amdgcn_s_setprio(1);                                          \
    _Pragma("unroll") for (int ni = 0; ni < 2; ++ni) {                      \
      ACC[0][ni] = __builtin_amdgcn_mfma_f32_16x16x32_bf16(                 \
          af0[0], bfr[ni][0], ACC[0][ni], 0, 0, 0);                         \
      ACC[0][ni] = __builtin_amdgcn_mfma_f32_16x16x32_bf16(                 \
          af0[1], bfr[ni][1], ACC[0][ni], 0, 0, 0);                         \
      ACC[1][ni] = __builtin_amdgcn_mfma_f32_16x16x32_bf16(                 \
          af1[0], bfr[ni][0], ACC[1][ni], 0, 0, 0);                         \
      ACC[1][ni] = __builtin_amdgcn_mfma_f32_16x16x32_bf16(                 \
          af1[1], bfr[ni][1], ACC[1][ni], 0, 0, 0);                         \
    }                                                                       \
    __builtin_amdgcn_s_setprio(0);                                          \
    af0[0] = *(const bf16x8*)(sm + BK_ + wm * 8192 + 4096 + qkB0);          \
    af0[1] = *(const bf16x8*)(sm + BK_ + wm * 8192 + 4096 + qkB1);          \
    af1[0] = *(const bf16x8*)(sm + BK_ + wm * 8192 + 6144 + qkB0);          \
    af1[1] = *(const bf16x8*)(sm + BK_ + wm * 8192 + 6144 + qkB1);          \
    __builtin_amdgcn_s_setprio(1);                                          \
    _Pragma("unroll") for (int ni = 0; ni < 2; ++ni) {                      \
      ACC[2][ni] = __builtin_amdgcn_mfma_f32_16x16x32_bf16(                 \
          af0[0], bfr[ni][0], ACC[2][ni], 0, 0, 0);                         \
      ACC[2][ni] = __builtin_amdgcn_mfma_f32_16x16x32_bf16(                 \
          af0[1], bfr[ni][1], ACC[2][ni], 0, 0, 0);                         \
      ACC[3][ni] = __builtin_amdgcn_mfma_f32_16x16x32_bf16(                 \
          af1[0], bfr[ni][0], ACC[3][ni], 0, 0, 0);                         \
      ACC[3][ni] = __builtin_amdgcn_mfma_f32_16x16x32_bf16(                 \
          af1[1], bfr[ni][1], ACC[3][ni], 0, 0, 0);                         \
    }                                                                       \
    __builtin_amdgcn_s_setprio(0);                                          \
    __builtin_amdgcn_s_barrier();                                           \
  }

// -------- fused QKV GEMM: N = 3072 (Wq|Wk|Wv stacked in WT) ---------------
// Grid 1536 = 6 exact rounds. XCD-contiguous: XCD k owns m-panels
// [8k,8k+8) x all 24 n-tiles -> A/XCD = 2 MB (L2-resident, fetched once).
__global__ __launch_bounds__(512, 2) void k_gemm_qkv8(
    const bf16* __restrict__ A, const bf16* __restrict__ BT,
    const float* __restrict__ bq, const float* __restrict__ bk,
    const float* __restrict__ bv, bf16* __restrict__ out, float qscale) {
  __shared__ __align__(16) char sm[65536];
  const int b0 = blockIdx.x;
  const int blk = (b0 & 7) * 192 + (b0 >> 3);
  const int m0 = (blk / 24) * 128, n0 = (blk % 24) * 128;
  GEMM_CORE(acc)
  // epilogue: row = m0 + wm*64 + mi*16 + g*4 + r; col = n0 + wn*32 + ni*16 + q16
#pragma unroll
  for (int ni = 0; ni < 2; ++ni) {
    int colBase = n0 + wn * 32 + ni * 16;
    int which = colBase >> 10;  // 0=Q 1=K 2=V
    const float* bp = (which == 0) ? bq : (which == 1) ? bk : bv;
    float scl = (which == 0) ? qscale : 1.0f;
    float bval = bp[(colBase & 1023) + q16];
    int hh = (colBase >> 6) & 15;
    int dd = (colBase & 63) + q16;
    size_t obase = (size_t)which * 8388608 + (size_t)hh * (Tn * HD) + dd;
#pragma unroll
    for (int mi = 0; mi < 4; ++mi) {
#pragma unroll
      for (int r = 0; r < 4; ++r) {
        int row = m0 + wm * 64 + mi * 16 + g * 4 + r;
        int bb = row >> 11, tt = row & 2047;
        out[obase + ((size_t)bb * Hn * Tn + tt) * HD] =
            (bf16)((acc[mi][ni][r] + bval) * scl);
      }
    }
  }
}

// -------- output projection GEMM: out fp32 flat [M][C], same core ---------
// Grid 512 = 2 exact rounds. XCD k: m-panels [8k,8k+8) x 8 n -> A 2MB + B
// 2MB both L2-fit.
__global__ __launch_bounds__(512, 2) void k_gemm_o8(
    const bf16* __restrict__ A, const bf16* __restrict__ BT,
    const float* __restrict__ bias, float* __restrict__ out) {
  __shared__ __align__(16) char sm[65536];
  const int b0 = blockIdx.x;
  const int blk = (b0 & 7) * 64 + (b0 >> 3);
  const int m0 = (blk >> 3) * 128, n0 = (blk & 7) * 128;
  GEMM_CORE(acc)
#pragma unroll
  for (int ni = 0; ni < 2; ++ni) {
    int col = n0 + wn * 32 + ni * 16 + q16;
    float bv = bias[col];
#pragma unroll
    for (int mi = 0; mi < 4; ++mi) {
#pragma unroll
      for (int r = 0; r < 4; ++r) {
        int row = m0 + wm * 64 + mi * 16 + g * 4 + r;
        out[(size_t)row * Cn + col] = acc[mi][ni][r] + bv;
      }
    }
  }
}

// ---------------- flash attention (causal), 8-wave QBLK=128 ----------------
__global__ __launch_bounds__(512, 4) void k_attn(const bf16* __restrict__ Q,
                                                 const bf16* __restrict__ K,
                                                 const bf16* __restrict__ V,
                                                 bf16* __restrict__ Y) {
  __shared__ __align__(16) char smem[32768];
  const int t = threadIdx.x, w = t >> 6, l = t & 63;
  const int g = l >> 4, q16 = l & 15;
  const int wg = blockIdx.x;
  const int bh = wg & 63;                      // low bits -> XCD pinning
  const int qtile = 15 - (wg >> 6);            // heavy tiles first
  const size_t base = (size_t)bh * Tn * HD;
  const bf16* Qh = Q + base;
  const bf16* Vh = V + base;
  const int qg = qtile * 128 + w * 16 + q16;   // this lane's q row

  bf16x8 aq[2];
#pragma unroll
  for (int kc = 0; kc < 2; ++kc)
    aq[kc] = *(const bf16x8*)(Qh + (size_t)qg * HD + kc * 32 + g * 8);

  const int xm = (q16 & 7) << 4;
  const int qkB0 = q16 * 128 + ((g * 16) ^ xm);
  const int qkB1 = q16 * 128 + ((64 + g * 16) ^ xm);
  const int innerL = (l >> 5) * 64 + ((l & 15) >> 2) * 16 +
                     (((l >> 4) & 1) * 4 + (l & 3)) * 2;
  int stb[8];
#pragma unroll
  for (int j = 0; j < 8; ++j)
    stb[j] = w * 1024 + j * 128 + (innerL ^ (j << 4));

  const int krow = w * 8 + (l >> 3);
  const int kseg = (l & 7) ^ (krow & 7);
  const bf16* kP = K + base + (size_t)krow * HD + kseg * 8;
  const bf16* vP = Vh + (size_t)l * HD + w * 8;

  f32x4 yacc[4] = {};
  float m_ = -1e30f, l_ = 0.f;
  const int nt = 2 * qtile + 2;
  const int it_mask = 2 * qtile + (w >= 4 ? 1 : 0);
  const int diag = (w & 3) * 16 + q16;

#define STAGE_K(KBUF)                           \
  {                                             \
    gl_lds16(kP, smem + (KBUF) + w * 1024);     \
    kP += 4096;                                 \
  }
#define WRITE_V(VBUF, a0)                               \
  {                                                     \
    _Pragma("unroll") for (int j = 0; j < 8; ++j)       \
      *(bf16*)(smem + (VBUF) + stb[j]) = a0[j];         \
  }
#define COMPUTE(KBUF, VBUF, DOMASK)                                          \
  {                                                                          \
    f32x4 s[4] = {};                                                         \
    __builtin_amdgcn_s_setprio(1);                                           \
    _Pragma("unroll") for (int nj = 0; nj < 4; ++nj) {                       \
      bf16x8 ak0 = *(const bf16x8*)(smem + (KBUF) + qkB0 + nj * 2048);       \
      s[nj] = __builtin_amdgcn_mfma_f32_16x16x32_bf16(ak0, aq[0], s[nj], 0, 0, 0); \
      bf16x8 ak1 = *(const bf16x8*)(smem + (KBUF) + qkB1 + nj * 2048);       \
      s[nj] = __builtin_amdgcn_mfma_f32_16x16x32_bf16(ak1, aq[1], s[nj], 0, 0, 0); \
    }                                                                        \
    __builtin_amdgcn_s_setprio(0);                                           \
    if (DOMASK) {                                                            \
      _Pragma("unroll") for (int nj = 0; nj < 4; ++nj)                       \
        _Pragma("unroll") for (int r = 0; r < 4; ++r)                        \
          if (nj * 16 + g * 4 + r > diag) s[nj][r] = -1e30f;                 \
    }                                                                        \
    float mx = fmaxf(fmaxf(fmaxf(s[0][0], s[0][1]), fmaxf(s[0][2], s[0][3])),\
                     fmaxf(fmaxf(s[1][0], s[1][1]), fmaxf(s[1][2], s[1][3])));\
    mx = fmaxf(mx, fmaxf(fmaxf(fmaxf(s[2][0], s[2][1]), fmaxf(s[2][2], s[2][3])),\
                         fmaxf(fmaxf(s[3][0], s[3][1]), fmaxf(s[3][2], s[3][3]))));\
    mx = fmaxf(mx, __shfl_xor(mx, 16));                                      \
    mx = fmaxf(mx, __shfl_xor(mx, 32));                                      \
    float mn = fmaxf(m_, mx);                                                \
    float fac = __builtin_amdgcn_exp2f(m_ - mn);                             \
    m_ = mn;                                                                 \
    float rs = 0.f;                                                          \
    _Pragma("unroll") for (int nj = 0; nj < 4; ++nj)                         \
      _Pragma("unroll") for (int r = 0; r < 4; ++r) {                        \
        float pv = __builtin_amdgcn_exp2f(s[nj][r] - mn);                    \
        s[nj][r] = pv;                                                       \
        rs += pv;                                                            \
      }                                                                      \
    rs += __shfl_xor(rs, 16);                                                \
    rs += __shfl_xor(rs, 32);                                                \
    l_ = l_ * fac + rs;                                                      \
    _Pragma("unroll") for (int ni = 0; ni < 4; ++ni)                         \
      _Pragma("unroll") for (int r = 0; r < 4; ++r) yacc[ni][r] *= fac;      \
    __builtin_amdgcn_s_setprio(1);                                           \
    _Pragma("unroll") for (int vkc = 0; vkc < 2; ++vkc) {                    \
      bf16x8 pb;                                                             \
      _Pragma("unroll") for (int j = 0; j < 4; ++j) {                        \
        pb[j] = (bf16)s[2 * vkc][j];                                         \
        pb[4 + j] = (bf16)s[2 * vkc + 1][j];                                 \
      }                                                                      \
      int vb = (vkc == 0) ? qkB0 : qkB1;                                     \
      _Pragma("unroll") for (int ni = 0; ni < 4; ++ni) {                     \
        bf16x8 va = *(const bf16x8*)(smem + (VBUF) + vb + ni * 2048);        \
        yacc[ni] = __builtin_amdgcn_mfma_f32_16x16x32_bf16(va, pb, yacc[ni], 0, 0, 0); \
      }                                                                      \
    }                                                                        \
    __builtin_amdgcn_s_setprio(0);                                           \
  }

  STAGE_K(0);
  {
    bf16x8 a0 = *(const bf16x8*)vP;
    vP += 4096;
    WRITE_V(16384, a0);
  }

  int it = 0;
  for (;;) {
    __syncthreads();
    bool more = (it + 1) < nt;
    bf16x8 a0;
    if (more) {
      STAGE_K(8192);
      a0 = *(const bf16x8*)vP;
      vP += 4096;
    }
    if (it <= it_mask) COMPUTE(0, 16384, it == it_mask);
    if (more) WRITE_V(24576, a0);
    if (++it >= nt) break;

    __syncthreads();
    more = (it + 1) < nt;
    if (more) {
      STAGE_K(0);
      a0 = *(const bf16x8*)vP;
      vP += 4096;
    }
    if (it <= it_mask) COMPUTE(8192, 24576, it == it_mask);
    if (more) WRITE_V(16384, a0);
    if (++it >= nt) break;
  }
#undef STAGE_K
#undef WRITE_V
#undef COMPUTE

  const int hh = bh & 15, bb = bh >> 4;
  float inv = 1.f / l_;
#pragma unroll
  for (int ni = 0; ni < 4; ++ni) {
    bf16x4 o;
#pragma unroll
    for (int r = 0; r < 4; ++r) o[r] = (bf16)(yacc[ni][r] * inv);
    int d0 = ni * 16 + g * 4;
    *(bf16x4*)&Y[(size_t)(bb * Tn + qg) * Cn + hh * HD + d0] = o;
  }
}

extern "C" void kernel_launch(void* const* d_in, const int* in_sizes, int n_in,
                              void* d_out, int out_size, void* d_ws,
                              size_t ws_size, hipStream_t stream) {
  const float* x  = (const float*)d_in[0];
  const float* Wq = (const float*)d_in[1];
  const float* bq = (const float*)d_in[2];
  const float* Wk = (const float*)d_in[3];
  const float* bk = (const float*)d_in[4];
  const float* Wv = (const float*)d_in[5];
  const float* bv = (const float*)d_in[6];
  const float* Wo = (const float*)d_in[7];
  const float* bo = (const float*)d_in[8];
  char* ws = (char*)d_ws;
  bf16* xb = (bf16*)ws;                          // 16MB, reused as y
  bf16* WT = (bf16*)(ws + (size_t)(16 << 20));   // 8MB (4 x 1M elems)
  bf16* Qh = (bf16*)(ws + (size_t)(24 << 20));   // 16MB (K,V follow)
  bf16* Kh = (bf16*)(ws + (size_t)(40 << 20));
  bf16* Vh = (bf16*)(ws + (size_t)(56 << 20));
  float* out = (float*)d_out;                    // reference output is fp32

  const float QSCALE = 0.125f * 1.44269504088896f;  // 1/sqrt(64) * log2(e)

  k_cvt_x<<<4096, 256, 0, stream>>>(x, xb);
  k_tw<<<dim3(32, 32, 4), 256, 0, stream>>>(Wq, Wk, Wv, Wo, WT);
  k_gemm_qkv8<<<1536, 512, 0, stream>>>(xb, WT, bq, bk, bv, Qh, QSCALE);
  k_attn<<<1024, 512, 0, stream>>>(Qh, Kh, Vh, xb);
  k_gemm_o8<<<512, 512, 0, stream>>>(xb, WT + (3u << 20), bo, out);
}